// Round 15
// baseline (143.288 us; speedup 1.0000x reference)
//
#include <hip/hip_runtime.h>

// ---------- types ----------
typedef __attribute__((ext_vector_type(8))) short bf16x8;   // 8 bf16 = 4 VGPR
typedef __attribute__((ext_vector_type(4))) float f32x4;
typedef __attribute__((ext_vector_type(16))) float f32x16;

#define MFMA16(A, B, C) __builtin_amdgcn_mfma_f32_16x16x32_bf16((A), (B), (C), 0, 0, 0)
#define MFMA32(A, B, C) __builtin_amdgcn_mfma_f32_32x32x16_bf16((A), (B), (C), 0, 0, 0)

union U8 { unsigned u[4]; bf16x8 v; };

// fp32 -> bf16 (round-to-nearest-even), header-independent
__device__ __forceinline__ unsigned short f2b(float f) {
  unsigned u = __builtin_bit_cast(unsigned, f);
  unsigned r = (u + 0x7fffu + ((u >> 16) & 1u)) >> 16;
  return (unsigned short)r;
}
__device__ __forceinline__ float b2f(unsigned short u) {
  unsigned v = ((unsigned)u) << 16;
  return __builtin_bit_cast(float, v);
}

// packed f32x2 -> bf16x2
__device__ __forceinline__ unsigned cvtpk(float lo, float hi) {
  unsigned r;
  asm("v_cvt_pk_bf16_f32 %0, %1, %2" : "=v"(r) : "v"(lo), "v"(hi));
  return r;
}
// exchange a.hi-half <-> b.lo-half across lane32 boundary.
// NOTE: operands MUST be distinct values — identical inputs get coalesced
// into one VGPR and the swap corrupts the reduction (R13 NaN bug).
__device__ __forceinline__ void swap32(unsigned& a, unsigned& b) {
  asm("v_permlane32_swap_b32 %0, %1" : "+v"(a), "+v"(b));
}

// async global->LDS, 16B per lane. dest = wave-uniform base + lane*16
__device__ __forceinline__ void gload16(const void* g, void* l) {
  __builtin_amdgcn_global_load_lds(
      (const __attribute__((address_space(1))) void*)g,
      (__attribute__((address_space(3))) void*)l, 16, 0, 0);
}

// ---------- pre-pass: fp32 -> bf16 (vectorized) ----------
__global__ void conv_bf16_kernel(const float* __restrict__ src,
                                 unsigned short* __restrict__ dst, int n) {
  int i = (blockIdx.x * blockDim.x + threadIdx.x) * 4;
  if (i < n) {
    float4 v = *(const float4*)(src + i);
    ushort4 o;
    o.x = f2b(v.x); o.y = f2b(v.y); o.z = f2b(v.z); o.w = f2b(v.w);
    *(ushort4*)(dst + i) = o;
  }
}

// ---------- pre-pass: transpose fp32 [1024][C] -> bf16 [C][1024], both W ----
__global__ __launch_bounds__(1024) void transpose2_bf16_kernel(
    const float* __restrict__ s1, unsigned short* __restrict__ d1,
    const float* __restrict__ s2, unsigned short* __restrict__ d2) {
  __shared__ unsigned short t[32][33];
  int bx = (int)blockIdx.x;
  const float* src;
  unsigned short* dst;
  int C;
  if (bx < 96) { src = s1; dst = d1; C = 3072; }
  else         { src = s2; dst = d2; C = 1024; bx -= 96; }
  int x = threadIdx.x, y = threadIdx.y;
  int c0 = bx * 32, r0 = blockIdx.y * 32;
  t[y][x] = f2b(src[(size_t)(r0 + y) * C + c0 + x]);
  __syncthreads();
  dst[(size_t)(c0 + y) * 1024 + r0 + x] = t[x][y];
}

// ---------- GEMM: C[M,N] = A[M,K] * Bt[N,K]^T (+bias), bf16 MFMA ----------
// Double-buffered prefetch (2-phase): STAGE(t+1) issued BEFORE compute(t),
// single barrier per K-step at the bottom. Stage latency hides under the
// 32-MFMA + 16-ds_read compute of the current tile (vs the old
// {sync;STAGE;sync;compute} which drained the just-issued stage every step).
template <int MODE>
__global__ __launch_bounds__(256, 2) void gemm_bf16_kernel(
    const unsigned short* __restrict__ A, const unsigned short* __restrict__ Bt,
    const float* __restrict__ bias, int M, int N, int K,
    unsigned short* __restrict__ q_bf, unsigned short* __restrict__ k_bf,
    unsigned short* __restrict__ vt_bf, float* __restrict__ k_out,
    float* __restrict__ v_out, float* __restrict__ y_out) {
  __shared__ __align__(16) unsigned short As[2][128 * 64];
  __shared__ __align__(16) unsigned short Bs[2][128 * 64];
  const int tid = threadIdx.x;
  const int lane = tid & 63, wid = tid >> 6;
  const int wr = wid >> 1, wc = wid & 1;
  const int l15 = lane & 15, lg = lane >> 4;
  const int m0 = blockIdx.y * 128, n0 = blockIdx.x * 128;

  f32x4 acc[4][4] = {};

  int rowS[4], colS[4];
#pragma unroll
  for (int j = 0; j < 4; ++j) {
    int L = j * 4096 + wid * 1024 + lane * 16;  // linear LDS byte
    int row = L >> 7;
    int c = (L & 127) ^ ((row & 7) << 4);
    rowS[j] = row;
    colS[j] = c >> 1;  // bf16 elements
  }

#define GSTAGE(KI, BUF)                                                         \
  {                                                                             \
    const int kt_ = (KI) * 64;                                                  \
    _Pragma("unroll") for (int j = 0; j < 4; ++j) {                             \
      gload16(A + (size_t)(m0 + rowS[j]) * K + kt_ + colS[j],                   \
              (char*)As[BUF] + j * 4096 + wid * 1024);                          \
      gload16(Bt + (size_t)(n0 + rowS[j]) * K + kt_ + colS[j],                  \
              (char*)Bs[BUF] + j * 4096 + wid * 1024);                          \
    }                                                                           \
  }

  const int nk = K >> 6;
  GSTAGE(0, 0);
  __syncthreads();  // stage(0) landed

  int cur = 0;
  for (int ki = 0; ki < nk; ++ki) {
    if (ki + 1 < nk) GSTAGE(ki + 1, cur ^ 1);  // prefetch next tile

    bf16x8 af[4][2], bfr[4][2];
#pragma unroll
    for (int i = 0; i < 4; ++i)
#pragma unroll
      for (int kk = 0; kk < 2; ++kk) {
        int ra = wr * 64 + i * 16 + l15;
        int cb = kk * 64 + lg * 16;
        af[i][kk] = *(const bf16x8*)((const char*)As[cur] + ra * 128 + (cb ^ ((ra & 7) << 4)));
        int rb = wc * 64 + i * 16 + l15;
        bfr[i][kk] = *(const bf16x8*)((const char*)Bs[cur] + rb * 128 + (cb ^ ((rb & 7) << 4)));
      }
#pragma unroll
    for (int mi = 0; mi < 4; ++mi)
#pragma unroll
      for (int ni = 0; ni < 4; ++ni)
#pragma unroll
        for (int kk = 0; kk < 2; ++kk)
          acc[mi][ni] = MFMA16(af[mi][kk], bfr[ni][kk], acc[mi][ni]);

    __syncthreads();  // drains stage(ki+1); all waves done reading buf cur
    cur ^= 1;
  }
#undef GSTAGE

#pragma unroll
  for (int ni = 0; ni < 4; ++ni) {
    int gn = n0 + wc * 64 + ni * 16 + l15;
    float bv = bias[gn];
    if (MODE == 0) {
      int which = gn >> 10, rem = gn & 1023;
      int h = rem >> 6, dh = rem & 63;
#pragma unroll
      for (int mi = 0; mi < 4; ++mi) {
        int gmb = m0 + wr * 64 + mi * 16 + lg * 4;
#pragma unroll
        for (int r = 0; r < 4; ++r) {
          int gm = gmb + r;
          int b = gm >> 11, t = gm & 2047;
          float val = acc[mi][ni][r] + bv;
          size_t idx = ((size_t)((b * 16 + h) * 2048 + t)) * 64 + dh;
          if (which == 0) {
            q_bf[idx] = f2b(val * 0.18033688f);  // pre-scale by 1/sqrt(64)*log2(e)
          } else if (which == 1) {
            k_out[idx] = val;
            k_bf[idx] = f2b(val);
          } else {
            v_out[idx] = val;
            vt_bf[((size_t)(b * 16 + h) * 64 + dh) * 2048 + t] = f2b(val);
          }
        }
      }
    } else {
#pragma unroll
      for (int mi = 0; mi < 4; ++mi) {
        int gmb = m0 + wr * 64 + mi * 16 + lg * 4;
#pragma unroll
        for (int r = 0; r < 4; ++r)
          y_out[(size_t)(gmb + r) * N + gn] = acc[mi][ni][r] + bv;
      }
    }
  }
}

// ---------- causal flash attention: split-K + softmax VALU diet -------------
// (unchanged from the passing R14 kernel)
__global__ __launch_bounds__(256, 2) void attn_kernel(
    const unsigned short* __restrict__ qbuf, const unsigned short* __restrict__ kb,
    const unsigned short* __restrict__ vtb, unsigned short* __restrict__ y_att,
    unsigned short* __restrict__ part_o, float2* __restrict__ part_ml) {
  __shared__ __align__(16) char lds_k[3][8192];
  __shared__ __align__(16) char lds_v[3][8192];
  const int tid = threadIdx.x, lane = tid & 63, w = tid >> 6;
  const int u = (int)blockIdx.x;  // 0..767
  int bh, qb, t0, t1, half, isplit;
  if (u < 512) {                  // split halves of qb 15..8 (heaviest first)
    isplit = 1;
    half = u & 1;
    int w2 = u >> 1;              // 0..255
    bh = w2 & 31;
    qb = 15 - (w2 >> 5);          // 15..8
    int ntf = 2 * qb + 2;
    t0 = half ? 16 : 0;
    t1 = half ? ntf : 16;
  } else {                        // whole blocks qb 7..0
    isplit = 0;
    half = 0;
    int s = u - 512;
    bh = s & 31;
    qb = 7 - (s >> 5);
    t0 = 0;
    t1 = 2 * qb + 2;
  }
  const int l31 = lane & 31, h = lane >> 5;
  const int qw0 = qb * 128 + w * 32;              // this wave's first q row
  const int qidx = qw0 + l31;
  const size_t base_off = (size_t)bh * (2048 * 64);
  const unsigned short* Q = qbuf + base_off;
  const char* Kb = (const char*)(kb + base_off);   // [2048][128B]
  const char* Vb = (const char*)(vtb + base_off);  // [64][4096B]
  const int my_last = (qw0 + 31) >> 6;  // last tile this wave computes

  // staging coords: LDS linear byte L holds global (row=L>>7, col=(L&127)^sw)
  int rowS[2], gcS[2];
#pragma unroll
  for (int j = 0; j < 2; ++j) {
    int L = tid * 16 + j * 4096;
    int row = L >> 7;
    rowS[j] = row;
    gcS[j] = (L & 127) ^ ((row & 7) << 4);
  }

#define STAGE(T, BUF)                                                           \
  if ((T) < t1) {                                                               \
    const int kv0_ = (T) * 64;                                                  \
    _Pragma("unroll") for (int j = 0; j < 2; ++j) {                             \
      gload16(Kb + (size_t)(kv0_ + rowS[j]) * 128 + gcS[j],                     \
              &lds_k[BUF][j * 4096 + tid * 16]);                                \
      gload16(Vb + (size_t)rowS[j] * 4096 + kv0_ * 2 + gcS[j],                  \
              &lds_v[BUF][j * 4096 + tid * 16]);                                \
    }                                                                           \
  }

  bf16x8 qB[4];
#pragma unroll
  for (int c = 0; c < 4; ++c)
    qB[c] = *(const bf16x8*)(Q + (size_t)(qw0 + l31) * 64 + c * 16 + h * 8);

  f32x16 yacc0 = {}, yacc1 = {};
  float m_run = -1e30f, l_run = 0.f;  // l_run is PER-LANE (half-row partial)
  const int swz = (l31 & 7) << 4;

  STAGE(t0, 0);
  STAGE(t0 + 1, 1);

  int rs = 0;  // (t - t0) % 3
  for (int t = t0; t < t1; ++t) {
    __syncthreads();  // drains stage(t+1) (issued a full iteration ago)
    const int wslot = rs < 1 ? rs + 2 : rs - 1;  // (t-t0+2)%3
    STAGE(t + 2, wslot);

    if (t <= my_last) {
      const char* Kl = lds_k[rs];
      const char* Vl = lds_v[rs];
      // QK^T for both key-halves
      __builtin_amdgcn_s_setprio(1);
      f32x16 st0 = {}, st1 = {};
#pragma unroll
      for (int c = 0; c < 4; ++c) {
        bf16x8 k0 = *(const bf16x8*)(Kl + (size_t)l31 * 128 + ((c * 32 + h * 16) ^ swz));
        st0 = MFMA32(k0, qB[c], st0);
      }
#pragma unroll
      for (int c = 0; c < 4; ++c) {
        bf16x8 k1 = *(const bf16x8*)(Kl + (size_t)(32 + l31) * 128 + ((c * 32 + h * 16) ^ swz));
        st1 = MFMA32(k1, qB[c], st1);
      }
      __builtin_amdgcn_s_setprio(0);

      if (t == my_last) {  // diagonal tile: causal mask, in place
#pragma unroll
        for (int r = 0; r < 16; ++r) {
          int key0 = t * 64 + (r & 3) + 8 * ((r >> 2) & 3) + 4 * h;
          st0[r] = (key0 > qidx) ? -1e30f : st0[r];
          st1[r] = (key0 + 32 > qidx) ? -1e30f : st1[r];
        }
      }
      // max tree, max3-fusable: 8 leaves of 4, then triple-fold
      float mx;
      {
        float v[8];
#pragma unroll
        for (int r = 0; r < 8; ++r)
          v[r] = fmaxf(fmaxf(st0[r], st0[r + 8]), fmaxf(st1[r], st1[r + 8]));
        float a = fmaxf(fmaxf(v[0], v[1]), v[2]);
        float b = fmaxf(fmaxf(v[3], v[4]), v[5]);
        float c = fmaxf(v[6], v[7]);
        mx = fmaxf(fmaxf(a, b), c);
      }
      mx = fmaxf(mx, __shfl_xor(mx, 32));  // cross-half row max
      if (__any(mx > m_run + 8.f)) {  // defer-max
        float mnew = fmaxf(m_run, mx);
        float alpha = exp2f(m_run - mnew);
#pragma unroll
        for (int r = 0; r < 16; ++r) { yacc0[r] *= alpha; yacc1[r] *= alpha; }
        l_run *= alpha;
        m_run = mnew;
      }
      float ls = 0.f;
#pragma unroll
      for (int r = 0; r < 16; ++r) {
        st0[r] = exp2f(st0[r] - m_run);
        ls += st0[r];
      }
#pragma unroll
      for (int r = 0; r < 16; ++r) {
        st1[r] = exp2f(st1[r] - m_run);
        ls += st1[r];
      }
      l_run += ls;  // per-lane; merged across halves after the loop

      // P -> bf16 fragments (keys chunked 16)
      U8 pf[4];
      {
        unsigned pk0 = cvtpk(st0[0], st0[1]), pk1 = cvtpk(st0[2], st0[3]);
        unsigned pk2 = cvtpk(st0[4], st0[5]), pk3 = cvtpk(st0[6], st0[7]);
        unsigned pk4 = cvtpk(st0[8], st0[9]), pk5 = cvtpk(st0[10], st0[11]);
        unsigned pk6 = cvtpk(st0[12], st0[13]), pk7 = cvtpk(st0[14], st0[15]);
        swap32(pk0, pk2); swap32(pk1, pk3); swap32(pk4, pk6); swap32(pk5, pk7);
        pf[0].u[0] = pk0; pf[0].u[1] = pk1; pf[0].u[2] = pk2; pf[0].u[3] = pk3;
        pf[1].u[0] = pk4; pf[1].u[1] = pk5; pf[1].u[2] = pk6; pf[1].u[3] = pk7;
        unsigned qk0 = cvtpk(st1[0], st1[1]), qk1 = cvtpk(st1[2], st1[3]);
        unsigned qk2 = cvtpk(st1[4], st1[5]), qk3 = cvtpk(st1[6], st1[7]);
        unsigned qk4 = cvtpk(st1[8], st1[9]), qk5 = cvtpk(st1[10], st1[11]);
        unsigned qk6 = cvtpk(st1[12], st1[13]), qk7 = cvtpk(st1[14], st1[15]);
        swap32(qk0, qk2); swap32(qk1, qk3); swap32(qk4, qk6); swap32(qk5, qk7);
        pf[2].u[0] = qk0; pf[2].u[1] = qk1; pf[2].u[2] = qk2; pf[2].u[3] = qk3;
        pf[3].u[0] = qk4; pf[3].u[1] = qk5; pf[3].u[2] = qk6; pf[3].u[3] = qk7;
      }

      // PV: Y^T += V^T * P^T
      __builtin_amdgcn_s_setprio(1);
#pragma unroll
      for (int c = 0; c < 4; ++c) {
        bf16x8 v0 = *(const bf16x8*)(Vl + (size_t)l31 * 128 + ((c * 32 + h * 16) ^ swz));
        yacc0 = MFMA32(v0, pf[c].v, yacc0);
      }
#pragma unroll
      for (int c = 0; c < 4; ++c) {
        bf16x8 v1 = *(const bf16x8*)(Vl + (size_t)(32 + l31) * 128 + ((c * 32 + h * 16) ^ swz));
        yacc1 = MFMA32(v1, pf[c].v, yacc1);
      }
      __builtin_amdgcn_s_setprio(0);
    }
    rs = rs < 2 ? rs + 1 : 0;
  }
#undef STAGE

  // merge the per-half l partials once
  float l_tot = l_run + __shfl_xor(l_run, 32);
  float inv = 1.f / l_tot;
  if (!isplit) {
    const int b = bh >> 4, head = bh & 15;
    size_t rowb = ((size_t)(b * 2048 + qw0 + l31) * 16 + head) * 64;
#pragma unroll
    for (int rg = 0; rg < 4; ++rg) {
      int d0 = 8 * rg + 4 * h;
      ushort4 o0, o1;
      o0.x = f2b(yacc0[4 * rg + 0] * inv);
      o0.y = f2b(yacc0[4 * rg + 1] * inv);
      o0.z = f2b(yacc0[4 * rg + 2] * inv);
      o0.w = f2b(yacc0[4 * rg + 3] * inv);
      *(ushort4*)(y_att + rowb + d0) = o0;
      o1.x = f2b(yacc1[4 * rg + 0] * inv);
      o1.y = f2b(yacc1[4 * rg + 1] * inv);
      o1.z = f2b(yacc1[4 * rg + 2] * inv);
      o1.w = f2b(yacc1[4 * rg + 3] * inv);
      *(ushort4*)(y_att + rowb + 32 + d0) = o1;
    }
  } else {
    // normalized bf16 partial tile [128][64] + per-row (m, l)
    const int p = ((15 - qb) << 5) | bh;  // 0..255
    unsigned short* po = part_o + (size_t)(p * 2 + half) * 8192;
    const int lrow = w * 32 + l31;
    size_t rowb = (size_t)lrow * 64;
#pragma unroll
    for (int rg = 0; rg < 4; ++rg) {
      int d0 = 8 * rg + 4 * h;
      ushort4 o0, o1;
      o0.x = f2b(yacc0[4 * rg + 0] * inv);
      o0.y = f2b(yacc0[4 * rg + 1] * inv);
      o0.z = f2b(yacc0[4 * rg + 2] * inv);
      o0.w = f2b(yacc0[4 * rg + 3] * inv);
      *(ushort4*)(po + rowb + d0) = o0;
      o1.x = f2b(yacc1[4 * rg + 0] * inv);
      o1.y = f2b(yacc1[4 * rg + 1] * inv);
      o1.z = f2b(yacc1[4 * rg + 2] * inv);
      o1.w = f2b(yacc1[4 * rg + 3] * inv);
      *(ushort4*)(po + rowb + 32 + d0) = o1;
    }
    if (h == 0) part_ml[(p * 2 + half) * 128 + lrow] = make_float2(m_run, l_tot);
  }
}

// ---------- merge the two KV-halves of each split output block ----------
__global__ __launch_bounds__(256) void attn_merge_kernel(
    const unsigned short* __restrict__ part_o, const float2* __restrict__ part_ml,
    unsigned short* __restrict__ y_att) {
  const int p = (int)blockIdx.x;  // 0..255
  const int qb = 15 - (p >> 5);
  const int bh = p & 31;
  const int tid = threadIdx.x;
  const int r = tid >> 1;           // 0..127
  const int c0 = (tid & 1) << 5;    // 0 or 32
  const unsigned short* o0 = part_o + (size_t)(p * 2 + 0) * 8192 + r * 64 + c0;
  const unsigned short* o1 = part_o + (size_t)(p * 2 + 1) * 8192 + r * 64 + c0;
  float2 ml0 = part_ml[(p * 2 + 0) * 128 + r];
  float2 ml1 = part_ml[(p * 2 + 1) * 128 + r];
  float mn = fmaxf(ml0.x, ml1.x);
  float w0 = ml0.y * exp2f(ml0.x - mn);
  float w1 = ml1.y * exp2f(ml1.x - mn);
  float inv = 1.f / (w0 + w1);
  w0 *= inv;
  w1 *= inv;
  const int b = bh >> 4, head = bh & 15;
  unsigned short* dst =
      y_att + ((size_t)(b * 2048 + qb * 128 + r) * 16 + head) * 64 + c0;
#pragma unroll
  for (int c = 0; c < 32; c += 4) {
    ushort4 a = *(const ushort4*)(o0 + c);
    ushort4 bb = *(const ushort4*)(o1 + c);
    ushort4 o;
    o.x = f2b(w0 * b2f(a.x) + w1 * b2f(bb.x));
    o.y = f2b(w0 * b2f(a.y) + w1 * b2f(bb.y));
    o.z = f2b(w0 * b2f(a.z) + w1 * b2f(bb.z));
    o.w = f2b(w0 * b2f(a.w) + w1 * b2f(bb.w));
    *(ushort4*)(dst + c) = o;
  }
}

// ---------- launcher ----------
extern "C" void kernel_launch(void* const* d_in, const int* in_sizes, int n_in,
                              void* d_out, int out_size, void* d_ws, size_t ws_size,
                              hipStream_t stream) {
  const float* x = (const float*)d_in[0];
  const float* W_qkv = (const float*)d_in[1];
  const float* b_qkv = (const float*)d_in[2];
  const float* W_out = (const float*)d_in[3];
  const float* b_out = (const float*)d_in[4];

  float* y_out = (float*)d_out;                 // [2,2048,1024]
  float* k_out = y_out + 4194304;               // [2,16,2048,64]
  float* v_out = y_out + 8388608;               // [2,16,2048,64]

  unsigned short* x_bf = (unsigned short*)d_ws;       // [4096,1024]
  unsigned short* wqkv_t = x_bf + 4194304;            // [3072,1024]
  unsigned short* wout_t = wqkv_t + 3145728;          // [1024,1024]
  unsigned short* q_bf = wout_t + 1048576;            // [B,H,T,Dh] (pre-scaled)
  unsigned short* k_bf = q_bf + 4194304;              // [B,H,T,Dh]
  unsigned short* vt_bf = k_bf + 4194304;             // [B,H,Dh,T]
  unsigned short* y_att = vt_bf + 4194304;            // [B,T,H*Dh]

  // attn partial buffers: reuse regions dead after GEMM0 (x_bf, wqkv_t)
  unsigned short* part_o = x_bf;                 // 512 x 8192 ushort = 8 MB
  float2* part_ml = (float2*)wqkv_t;             // 512 x 128 float2 = 512 KB

  conv_bf16_kernel<<<4096, 256, 0, stream>>>(x, x_bf, 4194304);
  transpose2_bf16_kernel<<<dim3(128, 32), dim3(32, 32), 0, stream>>>(
      W_qkv, wqkv_t, W_out, wout_t);
  gemm_bf16_kernel<0><<<dim3(24, 32), 256, 0, stream>>>(
      x_bf, wqkv_t, b_qkv, 4096, 3072, 1024, q_bf, k_bf, vt_bf, k_out, v_out, nullptr);
  attn_kernel<<<768, 256, 0, stream>>>(q_bf, k_bf, vt_bf, y_att, part_o, part_ml);
  attn_merge_kernel<<<256, 256, 0, stream>>>(part_o, part_ml, y_att);
  gemm_bf16_kernel<1><<<dim3(8, 32), 256, 0, stream>>>(
      y_att, wout_t, b_out, 4096, 1024, 1024, nullptr, nullptr, nullptr, nullptr, nullptr, y_out);
}

// Round 16
// 136.314 us; speedup vs baseline: 1.0512x; 1.0512x over previous
//
#include <hip/hip_runtime.h>

// ---------- types ----------
typedef __attribute__((ext_vector_type(8))) short bf16x8;   // 8 bf16 = 4 VGPR
typedef __attribute__((ext_vector_type(4))) float f32x4;
typedef __attribute__((ext_vector_type(16))) float f32x16;

#define MFMA16(A, B, C) __builtin_amdgcn_mfma_f32_16x16x32_bf16((A), (B), (C), 0, 0, 0)
#define MFMA32(A, B, C) __builtin_amdgcn_mfma_f32_32x32x16_bf16((A), (B), (C), 0, 0, 0)

union U8 { unsigned u[4]; bf16x8 v; };

// fp32 -> bf16 (round-to-nearest-even), header-independent
__device__ __forceinline__ unsigned short f2b(float f) {
  unsigned u = __builtin_bit_cast(unsigned, f);
  unsigned r = (u + 0x7fffu + ((u >> 16) & 1u)) >> 16;
  return (unsigned short)r;
}
__device__ __forceinline__ float b2f(unsigned short u) {
  unsigned v = ((unsigned)u) << 16;
  return __builtin_bit_cast(float, v);
}

// packed f32x2 -> bf16x2
__device__ __forceinline__ unsigned cvtpk(float lo, float hi) {
  unsigned r;
  asm("v_cvt_pk_bf16_f32 %0, %1, %2" : "=v"(r) : "v"(lo), "v"(hi));
  return r;
}
// exchange a.hi-half <-> b.lo-half across lane32 boundary.
// NOTE: operands MUST be distinct values — identical inputs get coalesced
// into one VGPR and the swap corrupts the reduction (R13 NaN bug).
__device__ __forceinline__ void swap32(unsigned& a, unsigned& b) {
  asm("v_permlane32_swap_b32 %0, %1" : "+v"(a), "+v"(b));
}

// async global->LDS, 16B per lane. dest = wave-uniform base + lane*16
__device__ __forceinline__ void gload16(const void* g, void* l) {
  __builtin_amdgcn_global_load_lds(
      (const __attribute__((address_space(1))) void*)g,
      (__attribute__((address_space(3))) void*)l, 16, 0, 0);
}

// ---------- pre-pass: fp32 -> bf16 (vectorized) ----------
__global__ void conv_bf16_kernel(const float* __restrict__ src,
                                 unsigned short* __restrict__ dst, int n) {
  int i = (blockIdx.x * blockDim.x + threadIdx.x) * 4;
  if (i < n) {
    float4 v = *(const float4*)(src + i);
    ushort4 o;
    o.x = f2b(v.x); o.y = f2b(v.y); o.z = f2b(v.z); o.w = f2b(v.w);
    *(ushort4*)(dst + i) = o;
  }
}

// ---------- pre-pass: transpose fp32 [1024][C] -> bf16 [C][1024], both W ----
__global__ __launch_bounds__(1024) void transpose2_bf16_kernel(
    const float* __restrict__ s1, unsigned short* __restrict__ d1,
    const float* __restrict__ s2, unsigned short* __restrict__ d2) {
  __shared__ unsigned short t[32][33];
  int bx = (int)blockIdx.x;
  const float* src;
  unsigned short* dst;
  int C;
  if (bx < 96) { src = s1; dst = d1; C = 3072; }
  else         { src = s2; dst = d2; C = 1024; bx -= 96; }
  int x = threadIdx.x, y = threadIdx.y;
  int c0 = bx * 32, r0 = blockIdx.y * 32;
  t[y][x] = f2b(src[(size_t)(r0 + y) * C + c0 + x]);
  __syncthreads();
  dst[(size_t)(c0 + y) * 1024 + r0 + x] = t[x][y];
}

// ---------- GEMM: C[M,N] = A[M,K] * Bt[N,K]^T (+bias), bf16 MFMA ----------
// BK=32 double-buffer: 2x(128x32) tiles per matrix = 32KB total LDS, so two
// blocks stay co-resident per CU (R15's 64KB variant dropped to 1 block/CU,
// occupancy 13.5%, and regressed). One barrier per K-step; STAGE(ki+1)
// issued before compute(ki) so the drain at the bottom barrier hits a
// ~1.5-iteration-old load. 64B rows: slot swizzle lg^((row>>1)&3) -> exact
// 2-way bank aliasing (free, m136); staging source pre-swizzled to match.
template <int MODE>
__global__ __launch_bounds__(256, 2) void gemm_bf16_kernel(
    const unsigned short* __restrict__ A, const unsigned short* __restrict__ Bt,
    const float* __restrict__ bias, int M, int N, int K,
    unsigned short* __restrict__ q_bf, unsigned short* __restrict__ k_bf,
    unsigned short* __restrict__ vt_bf, float* __restrict__ k_out,
    float* __restrict__ v_out, float* __restrict__ y_out) {
  __shared__ __align__(16) unsigned short As[2][128 * 32];
  __shared__ __align__(16) unsigned short Bs[2][128 * 32];
  const int tid = threadIdx.x;
  const int lane = tid & 63, wid = tid >> 6;
  const int wr = wid >> 1, wc = wid & 1;
  const int l15 = lane & 15, lg = lane >> 4;
  const int m0 = blockIdx.y * 128, n0 = blockIdx.x * 128;

  f32x4 acc[4][4] = {};

  // staging coords: LDS byte L holds global(row = L>>6,
  // elem-col = ((slot ^ ((row>>1)&3))<<3)), slot = (L>>4)&3
  int rowS[2], colS[2];
#pragma unroll
  for (int j = 0; j < 2; ++j) {
    int L = j * 4096 + tid * 16;
    int r = L >> 6;
    int s = (L >> 4) & 3;
    rowS[j] = r;
    colS[j] = (s ^ ((r >> 1) & 3)) << 3;
  }

#define GSTAGE(KI, BUF)                                                         \
  {                                                                             \
    const int kt_ = (KI) * 32;                                                  \
    _Pragma("unroll") for (int j = 0; j < 2; ++j) {                             \
      gload16(A + (size_t)(m0 + rowS[j]) * K + kt_ + colS[j],                   \
              (char*)As[BUF] + j * 4096 + tid * 16);                            \
      gload16(Bt + (size_t)(n0 + rowS[j]) * K + kt_ + colS[j],                  \
              (char*)Bs[BUF] + j * 4096 + tid * 16);                            \
    }                                                                           \
  }

  const int nk = K >> 5;
  GSTAGE(0, 0);
  __syncthreads();  // stage(0) landed

  int cur = 0;
  for (int ki = 0; ki < nk; ++ki) {
    if (ki + 1 < nk) GSTAGE(ki + 1, cur ^ 1);  // prefetch next K-tile

    bf16x8 af[4], bfr[4];
#pragma unroll
    for (int i = 0; i < 4; ++i) {
      int ra = wr * 64 + i * 16 + l15;
      af[i] = *(const bf16x8*)((const char*)As[cur] + ra * 64 +
                               ((lg ^ ((ra >> 1) & 3)) << 4));
      int rb = wc * 64 + i * 16 + l15;
      bfr[i] = *(const bf16x8*)((const char*)Bs[cur] + rb * 64 +
                                ((lg ^ ((rb >> 1) & 3)) << 4));
    }
#pragma unroll
    for (int mi = 0; mi < 4; ++mi)
#pragma unroll
      for (int ni = 0; ni < 4; ++ni)
        acc[mi][ni] = MFMA16(af[mi], bfr[ni], acc[mi][ni]);

    __syncthreads();  // drains stage(ki+1); all waves done reading buf cur
    cur ^= 1;
  }
#undef GSTAGE

#pragma unroll
  for (int ni = 0; ni < 4; ++ni) {
    int gn = n0 + wc * 64 + ni * 16 + l15;
    float bv = bias[gn];
    if (MODE == 0) {
      int which = gn >> 10, rem = gn & 1023;
      int h = rem >> 6, dh = rem & 63;
#pragma unroll
      for (int mi = 0; mi < 4; ++mi) {
        int gmb = m0 + wr * 64 + mi * 16 + lg * 4;
#pragma unroll
        for (int r = 0; r < 4; ++r) {
          int gm = gmb + r;
          int b = gm >> 11, t = gm & 2047;
          float val = acc[mi][ni][r] + bv;
          size_t idx = ((size_t)((b * 16 + h) * 2048 + t)) * 64 + dh;
          if (which == 0) {
            q_bf[idx] = f2b(val * 0.18033688f);  // pre-scale by 1/sqrt(64)*log2(e)
          } else if (which == 1) {
            k_out[idx] = val;
            k_bf[idx] = f2b(val);
          } else {
            v_out[idx] = val;
            vt_bf[((size_t)(b * 16 + h) * 64 + dh) * 2048 + t] = f2b(val);
          }
        }
      }
    } else {
#pragma unroll
      for (int mi = 0; mi < 4; ++mi) {
        int gmb = m0 + wr * 64 + mi * 16 + lg * 4;
#pragma unroll
        for (int r = 0; r < 4; ++r)
          y_out[(size_t)(gmb + r) * N + gn] = acc[mi][ni][r] + bv;
      }
    }
  }
}

// ---------- causal flash attention: split-K + softmax VALU diet -------------
// (unchanged from the passing R14 kernel)
__global__ __launch_bounds__(256, 2) void attn_kernel(
    const unsigned short* __restrict__ qbuf, const unsigned short* __restrict__ kb,
    const unsigned short* __restrict__ vtb, unsigned short* __restrict__ y_att,
    unsigned short* __restrict__ part_o, float2* __restrict__ part_ml) {
  __shared__ __align__(16) char lds_k[3][8192];
  __shared__ __align__(16) char lds_v[3][8192];
  const int tid = threadIdx.x, lane = tid & 63, w = tid >> 6;
  const int u = (int)blockIdx.x;  // 0..767
  int bh, qb, t0, t1, half, isplit;
  if (u < 512) {                  // split halves of qb 15..8 (heaviest first)
    isplit = 1;
    half = u & 1;
    int w2 = u >> 1;              // 0..255
    bh = w2 & 31;
    qb = 15 - (w2 >> 5);          // 15..8
    int ntf = 2 * qb + 2;
    t0 = half ? 16 : 0;
    t1 = half ? ntf : 16;
  } else {                        // whole blocks qb 7..0
    isplit = 0;
    half = 0;
    int s = u - 512;
    bh = s & 31;
    qb = 7 - (s >> 5);
    t0 = 0;
    t1 = 2 * qb + 2;
  }
  const int l31 = lane & 31, h = lane >> 5;
  const int qw0 = qb * 128 + w * 32;              // this wave's first q row
  const int qidx = qw0 + l31;
  const size_t base_off = (size_t)bh * (2048 * 64);
  const unsigned short* Q = qbuf + base_off;
  const char* Kb = (const char*)(kb + base_off);   // [2048][128B]
  const char* Vb = (const char*)(vtb + base_off);  // [64][4096B]
  const int my_last = (qw0 + 31) >> 6;  // last tile this wave computes

  // staging coords: LDS linear byte L holds global (row=L>>7, col=(L&127)^sw)
  int rowS[2], gcS[2];
#pragma unroll
  for (int j = 0; j < 2; ++j) {
    int L = tid * 16 + j * 4096;
    int row = L >> 7;
    rowS[j] = row;
    gcS[j] = (L & 127) ^ ((row & 7) << 4);
  }

#define STAGE(T, BUF)                                                           \
  if ((T) < t1) {                                                               \
    const int kv0_ = (T) * 64;                                                  \
    _Pragma("unroll") for (int j = 0; j < 2; ++j) {                             \
      gload16(Kb + (size_t)(kv0_ + rowS[j]) * 128 + gcS[j],                     \
              &lds_k[BUF][j * 4096 + tid * 16]);                                \
      gload16(Vb + (size_t)rowS[j] * 4096 + kv0_ * 2 + gcS[j],                  \
              &lds_v[BUF][j * 4096 + tid * 16]);                                \
    }                                                                           \
  }

  bf16x8 qB[4];
#pragma unroll
  for (int c = 0; c < 4; ++c)
    qB[c] = *(const bf16x8*)(Q + (size_t)(qw0 + l31) * 64 + c * 16 + h * 8);

  f32x16 yacc0 = {}, yacc1 = {};
  float m_run = -1e30f, l_run = 0.f;  // l_run is PER-LANE (half-row partial)
  const int swz = (l31 & 7) << 4;

  STAGE(t0, 0);
  STAGE(t0 + 1, 1);

  int rs = 0;  // (t - t0) % 3
  for (int t = t0; t < t1; ++t) {
    __syncthreads();  // drains stage(t+1) (issued a full iteration ago)
    const int wslot = rs < 1 ? rs + 2 : rs - 1;  // (t-t0+2)%3
    STAGE(t + 2, wslot);

    if (t <= my_last) {
      const char* Kl = lds_k[rs];
      const char* Vl = lds_v[rs];
      // QK^T for both key-halves
      __builtin_amdgcn_s_setprio(1);
      f32x16 st0 = {}, st1 = {};
#pragma unroll
      for (int c = 0; c < 4; ++c) {
        bf16x8 k0 = *(const bf16x8*)(Kl + (size_t)l31 * 128 + ((c * 32 + h * 16) ^ swz));
        st0 = MFMA32(k0, qB[c], st0);
      }
#pragma unroll
      for (int c = 0; c < 4; ++c) {
        bf16x8 k1 = *(const bf16x8*)(Kl + (size_t)(32 + l31) * 128 + ((c * 32 + h * 16) ^ swz));
        st1 = MFMA32(k1, qB[c], st1);
      }
      __builtin_amdgcn_s_setprio(0);

      if (t == my_last) {  // diagonal tile: causal mask, in place
#pragma unroll
        for (int r = 0; r < 16; ++r) {
          int key0 = t * 64 + (r & 3) + 8 * ((r >> 2) & 3) + 4 * h;
          st0[r] = (key0 > qidx) ? -1e30f : st0[r];
          st1[r] = (key0 + 32 > qidx) ? -1e30f : st1[r];
        }
      }
      // max tree, max3-fusable: 8 leaves of 4, then triple-fold
      float mx;
      {
        float v[8];
#pragma unroll
        for (int r = 0; r < 8; ++r)
          v[r] = fmaxf(fmaxf(st0[r], st0[r + 8]), fmaxf(st1[r], st1[r + 8]));
        float a = fmaxf(fmaxf(v[0], v[1]), v[2]);
        float b = fmaxf(fmaxf(v[3], v[4]), v[5]);
        float c = fmaxf(v[6], v[7]);
        mx = fmaxf(fmaxf(a, b), c);
      }
      mx = fmaxf(mx, __shfl_xor(mx, 32));  // cross-half row max
      if (__any(mx > m_run + 8.f)) {  // defer-max
        float mnew = fmaxf(m_run, mx);
        float alpha = exp2f(m_run - mnew);
#pragma unroll
        for (int r = 0; r < 16; ++r) { yacc0[r] *= alpha; yacc1[r] *= alpha; }
        l_run *= alpha;
        m_run = mnew;
      }
      float ls = 0.f;
#pragma unroll
      for (int r = 0; r < 16; ++r) {
        st0[r] = exp2f(st0[r] - m_run);
        ls += st0[r];
      }
#pragma unroll
      for (int r = 0; r < 16; ++r) {
        st1[r] = exp2f(st1[r] - m_run);
        ls += st1[r];
      }
      l_run += ls;  // per-lane; merged across halves after the loop

      // P -> bf16 fragments (keys chunked 16)
      U8 pf[4];
      {
        unsigned pk0 = cvtpk(st0[0], st0[1]), pk1 = cvtpk(st0[2], st0[3]);
        unsigned pk2 = cvtpk(st0[4], st0[5]), pk3 = cvtpk(st0[6], st0[7]);
        unsigned pk4 = cvtpk(st0[8], st0[9]), pk5 = cvtpk(st0[10], st0[11]);
        unsigned pk6 = cvtpk(st0[12], st0[13]), pk7 = cvtpk(st0[14], st0[15]);
        swap32(pk0, pk2); swap32(pk1, pk3); swap32(pk4, pk6); swap32(pk5, pk7);
        pf[0].u[0] = pk0; pf[0].u[1] = pk1; pf[0].u[2] = pk2; pf[0].u[3] = pk3;
        pf[1].u[0] = pk4; pf[1].u[1] = pk5; pf[1].u[2] = pk6; pf[1].u[3] = pk7;
        unsigned qk0 = cvtpk(st1[0], st1[1]), qk1 = cvtpk(st1[2], st1[3]);
        unsigned qk2 = cvtpk(st1[4], st1[5]), qk3 = cvtpk(st1[6], st1[7]);
        unsigned qk4 = cvtpk(st1[8], st1[9]), qk5 = cvtpk(st1[10], st1[11]);
        unsigned qk6 = cvtpk(st1[12], st1[13]), qk7 = cvtpk(st1[14], st1[15]);
        swap32(qk0, qk2); swap32(qk1, qk3); swap32(qk4, qk6); swap32(qk5, qk7);
        pf[2].u[0] = qk0; pf[2].u[1] = qk1; pf[2].u[2] = qk2; pf[2].u[3] = qk3;
        pf[3].u[0] = qk4; pf[3].u[1] = qk5; pf[3].u[2] = qk6; pf[3].u[3] = qk7;
      }

      // PV: Y^T += V^T * P^T
      __builtin_amdgcn_s_setprio(1);
#pragma unroll
      for (int c = 0; c < 4; ++c) {
        bf16x8 v0 = *(const bf16x8*)(Vl + (size_t)l31 * 128 + ((c * 32 + h * 16) ^ swz));
        yacc0 = MFMA32(v0, pf[c].v, yacc0);
      }
#pragma unroll
      for (int c = 0; c < 4; ++c) {
        bf16x8 v1 = *(const bf16x8*)(Vl + (size_t)(32 + l31) * 128 + ((c * 32 + h * 16) ^ swz));
        yacc1 = MFMA32(v1, pf[c].v, yacc1);
      }
      __builtin_amdgcn_s_setprio(0);
    }
    rs = rs < 2 ? rs + 1 : 0;
  }
#undef STAGE

  // merge the per-half l partials once
  float l_tot = l_run + __shfl_xor(l_run, 32);
  float inv = 1.f / l_tot;
  if (!isplit) {
    const int b = bh >> 4, head = bh & 15;
    size_t rowb = ((size_t)(b * 2048 + qw0 + l31) * 16 + head) * 64;
#pragma unroll
    for (int rg = 0; rg < 4; ++rg) {
      int d0 = 8 * rg + 4 * h;
      ushort4 o0, o1;
      o0.x = f2b(yacc0[4 * rg + 0] * inv);
      o0.y = f2b(yacc0[4 * rg + 1] * inv);
      o0.z = f2b(yacc0[4 * rg + 2] * inv);
      o0.w = f2b(yacc0[4 * rg + 3] * inv);
      *(ushort4*)(y_att + rowb + d0) = o0;
      o1.x = f2b(yacc1[4 * rg + 0] * inv);
      o1.y = f2b(yacc1[4 * rg + 1] * inv);
      o1.z = f2b(yacc1[4 * rg + 2] * inv);
      o1.w = f2b(yacc1[4 * rg + 3] * inv);
      *(ushort4*)(y_att + rowb + 32 + d0) = o1;
    }
  } else {
    // normalized bf16 partial tile [128][64] + per-row (m, l)
    const int p = ((15 - qb) << 5) | bh;  // 0..255
    unsigned short* po = part_o + (size_t)(p * 2 + half) * 8192;
    const int lrow = w * 32 + l31;
    size_t rowb = (size_t)lrow * 64;
#pragma unroll
    for (int rg = 0; rg < 4; ++rg) {
      int d0 = 8 * rg + 4 * h;
      ushort4 o0, o1;
      o0.x = f2b(yacc0[4 * rg + 0] * inv);
      o0.y = f2b(yacc0[4 * rg + 1] * inv);
      o0.z = f2b(yacc0[4 * rg + 2] * inv);
      o0.w = f2b(yacc0[4 * rg + 3] * inv);
      *(ushort4*)(po + rowb + d0) = o0;
      o1.x = f2b(yacc1[4 * rg + 0] * inv);
      o1.y = f2b(yacc1[4 * rg + 1] * inv);
      o1.z = f2b(yacc1[4 * rg + 2] * inv);
      o1.w = f2b(yacc1[4 * rg + 3] * inv);
      *(ushort4*)(po + rowb + 32 + d0) = o1;
    }
    if (h == 0) part_ml[(p * 2 + half) * 128 + lrow] = make_float2(m_run, l_tot);
  }
}

// ---------- merge the two KV-halves of each split output block ----------
__global__ __launch_bounds__(256) void attn_merge_kernel(
    const unsigned short* __restrict__ part_o, const float2* __restrict__ part_ml,
    unsigned short* __restrict__ y_att) {
  const int p = (int)blockIdx.x;  // 0..255
  const int qb = 15 - (p >> 5);
  const int bh = p & 31;
  const int tid = threadIdx.x;
  const int r = tid >> 1;           // 0..127
  const int c0 = (tid & 1) << 5;    // 0 or 32
  const unsigned short* o0 = part_o + (size_t)(p * 2 + 0) * 8192 + r * 64 + c0;
  const unsigned short* o1 = part_o + (size_t)(p * 2 + 1) * 8192 + r * 64 + c0;
  float2 ml0 = part_ml[(p * 2 + 0) * 128 + r];
  float2 ml1 = part_ml[(p * 2 + 1) * 128 + r];
  float mn = fmaxf(ml0.x, ml1.x);
  float w0 = ml0.y * exp2f(ml0.x - mn);
  float w1 = ml1.y * exp2f(ml1.x - mn);
  float inv = 1.f / (w0 + w1);
  w0 *= inv;
  w1 *= inv;
  const int b = bh >> 4, head = bh & 15;
  unsigned short* dst =
      y_att + ((size_t)(b * 2048 + qb * 128 + r) * 16 + head) * 64 + c0;
#pragma unroll
  for (int c = 0; c < 32; c += 4) {
    ushort4 a = *(const ushort4*)(o0 + c);
    ushort4 bb = *(const ushort4*)(o1 + c);
    ushort4 o;
    o.x = f2b(w0 * b2f(a.x) + w1 * b2f(bb.x));
    o.y = f2b(w0 * b2f(a.y) + w1 * b2f(bb.y));
    o.z = f2b(w0 * b2f(a.z) + w1 * b2f(bb.z));
    o.w = f2b(w0 * b2f(a.w) + w1 * b2f(bb.w));
    *(ushort4*)(dst + c) = o;
  }
}

// ---------- launcher ----------
extern "C" void kernel_launch(void* const* d_in, const int* in_sizes, int n_in,
                              void* d_out, int out_size, void* d_ws, size_t ws_size,
                              hipStream_t stream) {
  const float* x = (const float*)d_in[0];
  const float* W_qkv = (const float*)d_in[1];
  const float* b_qkv = (const float*)d_in[2];
  const float* W_out = (const float*)d_in[3];
  const float* b_out = (const float*)d_in[4];

  float* y_out = (float*)d_out;                 // [2,2048,1024]
  float* k_out = y_out + 4194304;               // [2,16,2048,64]
  float* v_out = y_out + 8388608;               // [2,16,2048,64]

  unsigned short* x_bf = (unsigned short*)d_ws;       // [4096,1024]
  unsigned short* wqkv_t = x_bf + 4194304;            // [3072,1024]
  unsigned short* wout_t = wqkv_t + 3145728;          // [1024,1024]
  unsigned short* q_bf = wout_t + 1048576;            // [B,H,T,Dh] (pre-scaled)
  unsigned short* k_bf = q_bf + 4194304;              // [B,H,T,Dh]
  unsigned short* vt_bf = k_bf + 4194304;             // [B,H,Dh,T]
  unsigned short* y_att = vt_bf + 4194304;            // [B,T,H*Dh]

  // attn partial buffers: reuse regions dead after GEMM0 (x_bf, wqkv_t)
  unsigned short* part_o = x_bf;                 // 512 x 8192 ushort = 8 MB
  float2* part_ml = (float2*)wqkv_t;             // 512 x 128 float2 = 512 KB

  conv_bf16_kernel<<<4096, 256, 0, stream>>>(x, x_bf, 4194304);
  transpose2_bf16_kernel<<<dim3(128, 32), dim3(32, 32), 0, stream>>>(
      W_qkv, wqkv_t, W_out, wout_t);
  gemm_bf16_kernel<0><<<dim3(24, 32), 256, 0, stream>>>(
      x_bf, wqkv_t, b_qkv, 4096, 3072, 1024, q_bf, k_bf, vt_bf, k_out, v_out, nullptr);
  attn_kernel<<<768, 256, 0, stream>>>(q_bf, k_bf, vt_bf, y_att, part_o, part_ml);
  attn_merge_kernel<<<256, 256, 0, stream>>>(part_o, part_ml, y_att);
  gemm_bf16_kernel<1><<<dim3(8, 32), 256, 0, stream>>>(
      y_att, wout_t, b_out, 4096, 1024, 1024, nullptr, nullptr, nullptr, nullptr, nullptr, y_out);
}

// Round 17
// 125.176 us; speedup vs baseline: 1.1447x; 1.0890x over previous
//
#include <hip/hip_runtime.h>

// ---------- types ----------
typedef __attribute__((ext_vector_type(8))) short bf16x8;   // 8 bf16 = 4 VGPR
typedef __attribute__((ext_vector_type(4))) float f32x4;
typedef __attribute__((ext_vector_type(16))) float f32x16;

#define MFMA16(A, B, C) __builtin_amdgcn_mfma_f32_16x16x32_bf16((A), (B), (C), 0, 0, 0)
#define MFMA32(A, B, C) __builtin_amdgcn_mfma_f32_32x32x16_bf16((A), (B), (C), 0, 0, 0)

union U8 { unsigned u[4]; bf16x8 v; };

// fp32 -> bf16 (round-to-nearest-even), header-independent
__device__ __forceinline__ unsigned short f2b(float f) {
  unsigned u = __builtin_bit_cast(unsigned, f);
  unsigned r = (u + 0x7fffu + ((u >> 16) & 1u)) >> 16;
  return (unsigned short)r;
}
__device__ __forceinline__ float b2f(unsigned short u) {
  unsigned v = ((unsigned)u) << 16;
  return __builtin_bit_cast(float, v);
}

// packed f32x2 -> bf16x2
__device__ __forceinline__ unsigned cvtpk(float lo, float hi) {
  unsigned r;
  asm("v_cvt_pk_bf16_f32 %0, %1, %2" : "=v"(r) : "v"(lo), "v"(hi));
  return r;
}
// exchange a.hi-half <-> b.lo-half across lane32 boundary.
// NOTE: operands MUST be distinct values — identical inputs get coalesced
// into one VGPR and the swap corrupts the reduction (R13 NaN bug).
__device__ __forceinline__ void swap32(unsigned& a, unsigned& b) {
  asm("v_permlane32_swap_b32 %0, %1" : "+v"(a), "+v"(b));
}

// async global->LDS, 16B per lane. dest = wave-uniform base + lane*16
__device__ __forceinline__ void gload16(const void* g, void* l) {
  __builtin_amdgcn_global_load_lds(
      (const __attribute__((address_space(1))) void*)g,
      (__attribute__((address_space(3))) void*)l, 16, 0, 0);
}

// ---------- fused pre-pass: x->bf16 copy + both weight transposes ----------
// blocks 0..1023: vectorized fp32->bf16 of x (4096 elems/block)
// blocks 1024..5119: 32x32 transpose tiles of W_qkv / W_out
__global__ __launch_bounds__(1024) void prepass_kernel(
    const float* __restrict__ x, unsigned short* __restrict__ x_bf,
    const float* __restrict__ s1, unsigned short* __restrict__ d1,
    const float* __restrict__ s2, unsigned short* __restrict__ d2) {
  __shared__ unsigned short t[32][33];
  const int bid = (int)blockIdx.x, tid = threadIdx.x;
  if (bid < 1024) {
    int i = (bid * 1024 + tid) * 4;
    float4 v = *(const float4*)(x + i);
    ushort4 o;
    o.x = f2b(v.x); o.y = f2b(v.y); o.z = f2b(v.z); o.w = f2b(v.w);
    *(ushort4*)(x_bf + i) = o;
    return;
  }
  int b = bid - 1024;
  int bx = b & 127, by = b >> 7;  // bx: col tile, by: row tile
  const float* src;
  unsigned short* dst;
  int C;
  if (bx < 96) { src = s1; dst = d1; C = 3072; }
  else         { src = s2; dst = d2; C = 1024; bx -= 96; }
  int xx = tid & 31, yy = tid >> 5;
  int c0 = bx * 32, r0 = by * 32;
  t[yy][xx] = f2b(src[(size_t)(r0 + yy) * C + c0 + xx]);
  __syncthreads();
  dst[(size_t)(c0 + yy) * 1024 + r0 + xx] = t[xx][yy];
}

// ---------- GEMM: C[M,N] = A[M,K] * Bt[N,K]^T (+bias), bf16 MFMA ----------
// R14-exact structure (single 128x64-per-matrix LDS buffer, 2 barriers/K-step
// — both double-buffer variants R15/R16 regressed). TM templated: 128 for
// MODE0 (grid 24x32 = 3 blocks/CU), 64 for MODE1 (grid 8x64 = 512 blocks =
// 2 blocks/CU; the old 8x32 grid was exactly 1 block/CU with no overlap).
template <int MODE, int TM>
__global__ __launch_bounds__(256, 2) void gemm_bf16_kernel(
    const unsigned short* __restrict__ A, const unsigned short* __restrict__ Bt,
    const float* __restrict__ bias, int M, int N, int K,
    unsigned short* __restrict__ q_bf, unsigned short* __restrict__ k_bf,
    unsigned short* __restrict__ vt_bf, float* __restrict__ k_out,
    float* __restrict__ v_out, float* __restrict__ y_out) {
  constexpr int MR = TM / 32;       // A-fragment rows per wave / stage chunks
  __shared__ __align__(16) unsigned short As[TM * 64];
  __shared__ __align__(16) unsigned short Bs[128 * 64];
  const int tid = threadIdx.x;
  const int lane = tid & 63, wid = tid >> 6;
  const int wr = wid >> 1, wc = wid & 1;
  const int l15 = lane & 15, lg = lane >> 4;
  const int m0 = blockIdx.y * TM, n0 = blockIdx.x * 128;

  f32x4 acc[MR][4] = {};

  int rowS[4], colS[4];
#pragma unroll
  for (int j = 0; j < 4; ++j) {
    int L = j * 4096 + tid * 16;  // linear LDS byte
    int row = L >> 7;
    int c = (L & 127) ^ ((row & 7) << 4);
    rowS[j] = row;
    colS[j] = c >> 1;  // bf16 elements
  }

  for (int kt = 0; kt < K; kt += 64) {
    __syncthreads();
#pragma unroll
    for (int j = 0; j < MR; ++j)
      gload16(A + (size_t)(m0 + rowS[j]) * K + kt + colS[j],
              (char*)As + j * 4096 + tid * 16);
#pragma unroll
    for (int j = 0; j < 4; ++j)
      gload16(Bt + (size_t)(n0 + rowS[j]) * K + kt + colS[j],
              (char*)Bs + j * 4096 + tid * 16);
    __syncthreads();

    bf16x8 af[MR][2], bfr[4][2];
#pragma unroll
    for (int i = 0; i < MR; ++i)
#pragma unroll
      for (int kk = 0; kk < 2; ++kk) {
        int ra = wr * (TM / 2) + i * 16 + l15;
        int cb = kk * 64 + lg * 16;
        af[i][kk] = *(const bf16x8*)((const char*)As + ra * 128 + (cb ^ ((ra & 7) << 4)));
      }
#pragma unroll
    for (int i = 0; i < 4; ++i)
#pragma unroll
      for (int kk = 0; kk < 2; ++kk) {
        int rb = wc * 64 + i * 16 + l15;
        int cb = kk * 64 + lg * 16;
        bfr[i][kk] = *(const bf16x8*)((const char*)Bs + rb * 128 + (cb ^ ((rb & 7) << 4)));
      }
#pragma unroll
    for (int mi = 0; mi < MR; ++mi)
#pragma unroll
      for (int ni = 0; ni < 4; ++ni)
#pragma unroll
        for (int kk = 0; kk < 2; ++kk)
          acc[mi][ni] = MFMA16(af[mi][kk], bfr[ni][kk], acc[mi][ni]);
  }

#pragma unroll
  for (int ni = 0; ni < 4; ++ni) {
    int gn = n0 + wc * 64 + ni * 16 + l15;
    float bv = bias[gn];
    if (MODE == 0) {
      int which = gn >> 10, rem = gn & 1023;
      int h = rem >> 6, dh = rem & 63;
#pragma unroll
      for (int mi = 0; mi < MR; ++mi) {
        int gmb = m0 + wr * (TM / 2) + mi * 16 + lg * 4;
#pragma unroll
        for (int r = 0; r < 4; ++r) {
          int gm = gmb + r;
          int b = gm >> 11, t = gm & 2047;
          float val = acc[mi][ni][r] + bv;
          size_t idx = ((size_t)((b * 16 + h) * 2048 + t)) * 64 + dh;
          if (which == 0) {
            q_bf[idx] = f2b(val * 0.18033688f);  // pre-scale by 1/sqrt(64)*log2(e)
          } else if (which == 1) {
            k_out[idx] = val;
            k_bf[idx] = f2b(val);
          } else {
            v_out[idx] = val;
            vt_bf[((size_t)(b * 16 + h) * 64 + dh) * 2048 + t] = f2b(val);
          }
        }
      }
    } else {
#pragma unroll
      for (int mi = 0; mi < MR; ++mi) {
        int gmb = m0 + wr * (TM / 2) + mi * 16 + lg * 4;
#pragma unroll
        for (int r = 0; r < 4; ++r)
          y_out[(size_t)(gmb + r) * N + gn] = acc[mi][ni][r] + bv;
      }
    }
  }
}

// ---------- causal flash attention: split-K + softmax VALU diet -------------
// (unchanged from the passing R14 kernel)
__global__ __launch_bounds__(256, 2) void attn_kernel(
    const unsigned short* __restrict__ qbuf, const unsigned short* __restrict__ kb,
    const unsigned short* __restrict__ vtb, unsigned short* __restrict__ y_att,
    unsigned short* __restrict__ part_o, float2* __restrict__ part_ml) {
  __shared__ __align__(16) char lds_k[3][8192];
  __shared__ __align__(16) char lds_v[3][8192];
  const int tid = threadIdx.x, lane = tid & 63, w = tid >> 6;
  const int u = (int)blockIdx.x;  // 0..767
  int bh, qb, t0, t1, half, isplit;
  if (u < 512) {                  // split halves of qb 15..8 (heaviest first)
    isplit = 1;
    half = u & 1;
    int w2 = u >> 1;              // 0..255
    bh = w2 & 31;
    qb = 15 - (w2 >> 5);          // 15..8
    int ntf = 2 * qb + 2;
    t0 = half ? 16 : 0;
    t1 = half ? ntf : 16;
  } else {                        // whole blocks qb 7..0
    isplit = 0;
    half = 0;
    int s = u - 512;
    bh = s & 31;
    qb = 7 - (s >> 5);
    t0 = 0;
    t1 = 2 * qb + 2;
  }
  const int l31 = lane & 31, h = lane >> 5;
  const int qw0 = qb * 128 + w * 32;              // this wave's first q row
  const int qidx = qw0 + l31;
  const size_t base_off = (size_t)bh * (2048 * 64);
  const unsigned short* Q = qbuf + base_off;
  const char* Kb = (const char*)(kb + base_off);   // [2048][128B]
  const char* Vb = (const char*)(vtb + base_off);  // [64][4096B]
  const int my_last = (qw0 + 31) >> 6;  // last tile this wave computes

  int rowS[2], gcS[2];
#pragma unroll
  for (int j = 0; j < 2; ++j) {
    int L = tid * 16 + j * 4096;
    int row = L >> 7;
    rowS[j] = row;
    gcS[j] = (L & 127) ^ ((row & 7) << 4);
  }

#define STAGE(T, BUF)                                                           \
  if ((T) < t1) {                                                               \
    const int kv0_ = (T) * 64;                                                  \
    _Pragma("unroll") for (int j = 0; j < 2; ++j) {                             \
      gload16(Kb + (size_t)(kv0_ + rowS[j]) * 128 + gcS[j],                     \
              &lds_k[BUF][j * 4096 + tid * 16]);                                \
      gload16(Vb + (size_t)rowS[j] * 4096 + kv0_ * 2 + gcS[j],                  \
              &lds_v[BUF][j * 4096 + tid * 16]);                                \
    }                                                                           \
  }

  bf16x8 qB[4];
#pragma unroll
  for (int c = 0; c < 4; ++c)
    qB[c] = *(const bf16x8*)(Q + (size_t)(qw0 + l31) * 64 + c * 16 + h * 8);

  f32x16 yacc0 = {}, yacc1 = {};
  float m_run = -1e30f, l_run = 0.f;  // l_run is PER-LANE (half-row partial)
  const int swz = (l31 & 7) << 4;

  STAGE(t0, 0);
  STAGE(t0 + 1, 1);

  int rs = 0;  // (t - t0) % 3
  for (int t = t0; t < t1; ++t) {
    __syncthreads();  // drains stage(t+1) (issued a full iteration ago)
    const int wslot = rs < 1 ? rs + 2 : rs - 1;  // (t-t0+2)%3
    STAGE(t + 2, wslot);

    if (t <= my_last) {
      const char* Kl = lds_k[rs];
      const char* Vl = lds_v[rs];
      __builtin_amdgcn_s_setprio(1);
      f32x16 st0 = {}, st1 = {};
#pragma unroll
      for (int c = 0; c < 4; ++c) {
        bf16x8 k0 = *(const bf16x8*)(Kl + (size_t)l31 * 128 + ((c * 32 + h * 16) ^ swz));
        st0 = MFMA32(k0, qB[c], st0);
      }
#pragma unroll
      for (int c = 0; c < 4; ++c) {
        bf16x8 k1 = *(const bf16x8*)(Kl + (size_t)(32 + l31) * 128 + ((c * 32 + h * 16) ^ swz));
        st1 = MFMA32(k1, qB[c], st1);
      }
      __builtin_amdgcn_s_setprio(0);

      if (t == my_last) {  // diagonal tile: causal mask, in place
#pragma unroll
        for (int r = 0; r < 16; ++r) {
          int key0 = t * 64 + (r & 3) + 8 * ((r >> 2) & 3) + 4 * h;
          st0[r] = (key0 > qidx) ? -1e30f : st0[r];
          st1[r] = (key0 + 32 > qidx) ? -1e30f : st1[r];
        }
      }
      float mx;
      {
        float v[8];
#pragma unroll
        for (int r = 0; r < 8; ++r)
          v[r] = fmaxf(fmaxf(st0[r], st0[r + 8]), fmaxf(st1[r], st1[r + 8]));
        float a = fmaxf(fmaxf(v[0], v[1]), v[2]);
        float b = fmaxf(fmaxf(v[3], v[4]), v[5]);
        float c = fmaxf(v[6], v[7]);
        mx = fmaxf(fmaxf(a, b), c);
      }
      mx = fmaxf(mx, __shfl_xor(mx, 32));  // cross-half row max
      if (__any(mx > m_run + 8.f)) {  // defer-max
        float mnew = fmaxf(m_run, mx);
        float alpha = exp2f(m_run - mnew);
#pragma unroll
        for (int r = 0; r < 16; ++r) { yacc0[r] *= alpha; yacc1[r] *= alpha; }
        l_run *= alpha;
        m_run = mnew;
      }
      float ls = 0.f;
#pragma unroll
      for (int r = 0; r < 16; ++r) {
        st0[r] = exp2f(st0[r] - m_run);
        ls += st0[r];
      }
#pragma unroll
      for (int r = 0; r < 16; ++r) {
        st1[r] = exp2f(st1[r] - m_run);
        ls += st1[r];
      }
      l_run += ls;  // per-lane; merged across halves after the loop

      U8 pf[4];
      {
        unsigned pk0 = cvtpk(st0[0], st0[1]), pk1 = cvtpk(st0[2], st0[3]);
        unsigned pk2 = cvtpk(st0[4], st0[5]), pk3 = cvtpk(st0[6], st0[7]);
        unsigned pk4 = cvtpk(st0[8], st0[9]), pk5 = cvtpk(st0[10], st0[11]);
        unsigned pk6 = cvtpk(st0[12], st0[13]), pk7 = cvtpk(st0[14], st0[15]);
        swap32(pk0, pk2); swap32(pk1, pk3); swap32(pk4, pk6); swap32(pk5, pk7);
        pf[0].u[0] = pk0; pf[0].u[1] = pk1; pf[0].u[2] = pk2; pf[0].u[3] = pk3;
        pf[1].u[0] = pk4; pf[1].u[1] = pk5; pf[1].u[2] = pk6; pf[1].u[3] = pk7;
        unsigned qk0 = cvtpk(st1[0], st1[1]), qk1 = cvtpk(st1[2], st1[3]);
        unsigned qk2 = cvtpk(st1[4], st1[5]), qk3 = cvtpk(st1[6], st1[7]);
        unsigned qk4 = cvtpk(st1[8], st1[9]), qk5 = cvtpk(st1[10], st1[11]);
        unsigned qk6 = cvtpk(st1[12], st1[13]), qk7 = cvtpk(st1[14], st1[15]);
        swap32(qk0, qk2); swap32(qk1, qk3); swap32(qk4, qk6); swap32(qk5, qk7);
        pf[2].u[0] = qk0; pf[2].u[1] = qk1; pf[2].u[2] = qk2; pf[2].u[3] = qk3;
        pf[3].u[0] = qk4; pf[3].u[1] = qk5; pf[3].u[2] = qk6; pf[3].u[3] = qk7;
      }

      __builtin_amdgcn_s_setprio(1);
#pragma unroll
      for (int c = 0; c < 4; ++c) {
        bf16x8 v0 = *(const bf16x8*)(Vl + (size_t)l31 * 128 + ((c * 32 + h * 16) ^ swz));
        yacc0 = MFMA32(v0, pf[c].v, yacc0);
      }
#pragma unroll
      for (int c = 0; c < 4; ++c) {
        bf16x8 v1 = *(const bf16x8*)(Vl + (size_t)(32 + l31) * 128 + ((c * 32 + h * 16) ^ swz));
        yacc1 = MFMA32(v1, pf[c].v, yacc1);
      }
      __builtin_amdgcn_s_setprio(0);
    }
    rs = rs < 2 ? rs + 1 : 0;
  }
#undef STAGE

  float l_tot = l_run + __shfl_xor(l_run, 32);
  float inv = 1.f / l_tot;
  if (!isplit) {
    const int b = bh >> 4, head = bh & 15;
    size_t rowb = ((size_t)(b * 2048 + qw0 + l31) * 16 + head) * 64;
#pragma unroll
    for (int rg = 0; rg < 4; ++rg) {
      int d0 = 8 * rg + 4 * h;
      ushort4 o0, o1;
      o0.x = f2b(yacc0[4 * rg + 0] * inv);
      o0.y = f2b(yacc0[4 * rg + 1] * inv);
      o0.z = f2b(yacc0[4 * rg + 2] * inv);
      o0.w = f2b(yacc0[4 * rg + 3] * inv);
      *(ushort4*)(y_att + rowb + d0) = o0;
      o1.x = f2b(yacc1[4 * rg + 0] * inv);
      o1.y = f2b(yacc1[4 * rg + 1] * inv);
      o1.z = f2b(yacc1[4 * rg + 2] * inv);
      o1.w = f2b(yacc1[4 * rg + 3] * inv);
      *(ushort4*)(y_att + rowb + 32 + d0) = o1;
    }
  } else {
    const int p = ((15 - qb) << 5) | bh;  // 0..255
    unsigned short* po = part_o + (size_t)(p * 2 + half) * 8192;
    const int lrow = w * 32 + l31;
    size_t rowb = (size_t)lrow * 64;
#pragma unroll
    for (int rg = 0; rg < 4; ++rg) {
      int d0 = 8 * rg + 4 * h;
      ushort4 o0, o1;
      o0.x = f2b(yacc0[4 * rg + 0] * inv);
      o0.y = f2b(yacc0[4 * rg + 1] * inv);
      o0.z = f2b(yacc0[4 * rg + 2] * inv);
      o0.w = f2b(yacc0[4 * rg + 3] * inv);
      *(ushort4*)(po + rowb + d0) = o0;
      o1.x = f2b(yacc1[4 * rg + 0] * inv);
      o1.y = f2b(yacc1[4 * rg + 1] * inv);
      o1.z = f2b(yacc1[4 * rg + 2] * inv);
      o1.w = f2b(yacc1[4 * rg + 3] * inv);
      *(ushort4*)(po + rowb + 32 + d0) = o1;
    }
    if (h == 0) part_ml[(p * 2 + half) * 128 + lrow] = make_float2(m_run, l_tot);
  }
}

// ---------- merge the two KV-halves of each split output block ----------
__global__ __launch_bounds__(256) void attn_merge_kernel(
    const unsigned short* __restrict__ part_o, const float2* __restrict__ part_ml,
    unsigned short* __restrict__ y_att) {
  const int p = (int)blockIdx.x;  // 0..255
  const int qb = 15 - (p >> 5);
  const int bh = p & 31;
  const int tid = threadIdx.x;
  const int r = tid >> 1;           // 0..127
  const int c0 = (tid & 1) << 5;    // 0 or 32
  const unsigned short* o0 = part_o + (size_t)(p * 2 + 0) * 8192 + r * 64 + c0;
  const unsigned short* o1 = part_o + (size_t)(p * 2 + 1) * 8192 + r * 64 + c0;
  float2 ml0 = part_ml[(p * 2 + 0) * 128 + r];
  float2 ml1 = part_ml[(p * 2 + 1) * 128 + r];
  float mn = fmaxf(ml0.x, ml1.x);
  float w0 = ml0.y * exp2f(ml0.x - mn);
  float w1 = ml1.y * exp2f(ml1.x - mn);
  float inv = 1.f / (w0 + w1);
  w0 *= inv;
  w1 *= inv;
  const int b = bh >> 4, head = bh & 15;
  unsigned short* dst =
      y_att + ((size_t)(b * 2048 + qb * 128 + r) * 16 + head) * 64 + c0;
#pragma unroll
  for (int c = 0; c < 32; c += 4) {
    ushort4 a = *(const ushort4*)(o0 + c);
    ushort4 bb = *(const ushort4*)(o1 + c);
    ushort4 o;
    o.x = f2b(w0 * b2f(a.x) + w1 * b2f(bb.x));
    o.y = f2b(w0 * b2f(a.y) + w1 * b2f(bb.y));
    o.z = f2b(w0 * b2f(a.z) + w1 * b2f(bb.z));
    o.w = f2b(w0 * b2f(a.w) + w1 * b2f(bb.w));
    *(ushort4*)(dst + c) = o;
  }
}

// ---------- launcher ----------
extern "C" void kernel_launch(void* const* d_in, const int* in_sizes, int n_in,
                              void* d_out, int out_size, void* d_ws, size_t ws_size,
                              hipStream_t stream) {
  const float* x = (const float*)d_in[0];
  const float* W_qkv = (const float*)d_in[1];
  const float* b_qkv = (const float*)d_in[2];
  const float* W_out = (const float*)d_in[3];
  const float* b_out = (const float*)d_in[4];

  float* y_out = (float*)d_out;                 // [2,2048,1024]
  float* k_out = y_out + 4194304;               // [2,16,2048,64]
  float* v_out = y_out + 8388608;               // [2,16,2048,64]

  unsigned short* x_bf = (unsigned short*)d_ws;       // [4096,1024]
  unsigned short* wqkv_t = x_bf + 4194304;            // [3072,1024]
  unsigned short* wout_t = wqkv_t + 3145728;          // [1024,1024]
  unsigned short* q_bf = wout_t + 1048576;            // [B,H,T,Dh] (pre-scaled)
  unsigned short* k_bf = q_bf + 4194304;              // [B,H,T,Dh]
  unsigned short* vt_bf = k_bf + 4194304;             // [B,H,Dh,T]
  unsigned short* y_att = vt_bf + 4194304;            // [B,T,H*Dh]

  // attn partial buffers: reuse regions dead after GEMM0 (x_bf, wqkv_t)
  unsigned short* part_o = x_bf;                 // 512 x 8192 ushort = 8 MB
  float2* part_ml = (float2*)wqkv_t;             // 512 x 128 float2 = 512 KB

  prepass_kernel<<<5120, 1024, 0, stream>>>(x, x_bf, W_qkv, wqkv_t, W_out, wout_t);
  gemm_bf16_kernel<0, 128><<<dim3(24, 32), 256, 0, stream>>>(
      x_bf, wqkv_t, b_qkv, 4096, 3072, 1024, q_bf, k_bf, vt_bf, k_out, v_out, nullptr);
  attn_kernel<<<768, 256, 0, stream>>>(q_bf, k_bf, vt_bf, y_att, part_o, part_ml);
  attn_merge_kernel<<<256, 256, 0, stream>>>(part_o, part_ml, y_att);
  gemm_bf16_kernel<1, 64><<<dim3(8, 64), 256, 0, stream>>>(
      y_att, wout_t, b_out, 4096, 1024, 1024, nullptr, nullptr, nullptr, nullptr, nullptr, y_out);
}

// Round 18
// 115.898 us; speedup vs baseline: 1.2363x; 1.0800x over previous
//
#include <hip/hip_runtime.h>

// ---------- types ----------
typedef __attribute__((ext_vector_type(8))) short bf16x8;   // 8 bf16 = 4 VGPR
typedef __attribute__((ext_vector_type(4))) float f32x4;
typedef __attribute__((ext_vector_type(16))) float f32x16;

#define MFMA16(A, B, C) __builtin_amdgcn_mfma_f32_16x16x32_bf16((A), (B), (C), 0, 0, 0)
#define MFMA32(A, B, C) __builtin_amdgcn_mfma_f32_32x32x16_bf16((A), (B), (C), 0, 0, 0)

union U8 { unsigned u[4]; bf16x8 v; };

// fp32 -> bf16 (round-to-nearest-even), header-independent
__device__ __forceinline__ unsigned short f2b(float f) {
  unsigned u = __builtin_bit_cast(unsigned, f);
  unsigned r = (u + 0x7fffu + ((u >> 16) & 1u)) >> 16;
  return (unsigned short)r;
}
__device__ __forceinline__ float b2f(unsigned short u) {
  unsigned v = ((unsigned)u) << 16;
  return __builtin_bit_cast(float, v);
}

// packed f32x2 -> bf16x2
__device__ __forceinline__ unsigned cvtpk(float lo, float hi) {
  unsigned r;
  asm("v_cvt_pk_bf16_f32 %0, %1, %2" : "=v"(r) : "v"(lo), "v"(hi));
  return r;
}
// exchange a.hi-half <-> b.lo-half across lane32 boundary.
// NOTE: operands MUST be distinct values — identical inputs get coalesced
// into one VGPR and the swap corrupts the reduction (R13 NaN bug).
__device__ __forceinline__ void swap32(unsigned& a, unsigned& b) {
  asm("v_permlane32_swap_b32 %0, %1" : "+v"(a), "+v"(b));
}

// async global->LDS, 16B per lane. dest = wave-uniform base + lane*16
__device__ __forceinline__ void gload16(const void* g, void* l) {
  __builtin_amdgcn_global_load_lds(
      (const __attribute__((address_space(1))) void*)g,
      (__attribute__((address_space(3))) void*)l, 16, 0, 0);
}

// ---------- fused pre-pass: x->bf16 copy + both weight transposes ----------
__global__ __launch_bounds__(1024) void prepass_kernel(
    const float* __restrict__ x, unsigned short* __restrict__ x_bf,
    const float* __restrict__ s1, unsigned short* __restrict__ d1,
    const float* __restrict__ s2, unsigned short* __restrict__ d2) {
  __shared__ unsigned short t[32][33];
  const int bid = (int)blockIdx.x, tid = threadIdx.x;
  if (bid < 1024) {
    int i = (bid * 1024 + tid) * 4;
    float4 v = *(const float4*)(x + i);
    ushort4 o;
    o.x = f2b(v.x); o.y = f2b(v.y); o.z = f2b(v.z); o.w = f2b(v.w);
    *(ushort4*)(x_bf + i) = o;
    return;
  }
  int b = bid - 1024;
  int bx = b & 127, by = b >> 7;  // bx: col tile, by: row tile
  const float* src;
  unsigned short* dst;
  int C;
  if (bx < 96) { src = s1; dst = d1; C = 3072; }
  else         { src = s2; dst = d2; C = 1024; bx -= 96; }
  int xx = tid & 31, yy = tid >> 5;
  int c0 = bx * 32, r0 = by * 32;
  t[yy][xx] = f2b(src[(size_t)(r0 + yy) * C + c0 + xx]);
  __syncthreads();
  dst[(size_t)(c0 + yy) * 1024 + r0 + xx] = t[xx][yy];
}

// ---------- GEMM: C[M,N] = A[M,K] * Bt[N,K]^T (+bias), bf16 MFMA ----------
// R14-exact structure (single buffer, 2 barriers/K-step — both double-buffer
// variants regressed). TM=128 for MODE0 (3 blocks/CU), TM=64 for MODE1
// (512 blocks = 2 blocks/CU).
template <int MODE, int TM>
__global__ __launch_bounds__(256, 2) void gemm_bf16_kernel(
    const unsigned short* __restrict__ A, const unsigned short* __restrict__ Bt,
    const float* __restrict__ bias, int M, int N, int K,
    unsigned short* __restrict__ q_bf, unsigned short* __restrict__ k_bf,
    unsigned short* __restrict__ vt_bf, float* __restrict__ k_out,
    float* __restrict__ v_out, float* __restrict__ y_out) {
  constexpr int MR = TM / 32;       // A-fragment rows per wave / stage chunks
  __shared__ __align__(16) unsigned short As[TM * 64];
  __shared__ __align__(16) unsigned short Bs[128 * 64];
  const int tid = threadIdx.x;
  const int lane = tid & 63, wid = tid >> 6;
  const int wr = wid >> 1, wc = wid & 1;
  const int l15 = lane & 15, lg = lane >> 4;
  const int m0 = blockIdx.y * TM, n0 = blockIdx.x * 128;

  f32x4 acc[MR][4] = {};

  int rowS[4], colS[4];
#pragma unroll
  for (int j = 0; j < 4; ++j) {
    int L = j * 4096 + tid * 16;  // linear LDS byte
    int row = L >> 7;
    int c = (L & 127) ^ ((row & 7) << 4);
    rowS[j] = row;
    colS[j] = c >> 1;  // bf16 elements
  }

  for (int kt = 0; kt < K; kt += 64) {
    __syncthreads();
#pragma unroll
    for (int j = 0; j < MR; ++j)
      gload16(A + (size_t)(m0 + rowS[j]) * K + kt + colS[j],
              (char*)As + j * 4096 + tid * 16);
#pragma unroll
    for (int j = 0; j < 4; ++j)
      gload16(Bt + (size_t)(n0 + rowS[j]) * K + kt + colS[j],
              (char*)Bs + j * 4096 + tid * 16);
    __syncthreads();

    bf16x8 af[MR][2], bfr[4][2];
#pragma unroll
    for (int i = 0; i < MR; ++i)
#pragma unroll
      for (int kk = 0; kk < 2; ++kk) {
        int ra = wr * (TM / 2) + i * 16 + l15;
        int cb = kk * 64 + lg * 16;
        af[i][kk] = *(const bf16x8*)((const char*)As + ra * 128 + (cb ^ ((ra & 7) << 4)));
      }
#pragma unroll
    for (int i = 0; i < 4; ++i)
#pragma unroll
      for (int kk = 0; kk < 2; ++kk) {
        int rb = wc * 64 + i * 16 + l15;
        int cb = kk * 64 + lg * 16;
        bfr[i][kk] = *(const bf16x8*)((const char*)Bs + rb * 128 + (cb ^ ((rb & 7) << 4)));
      }
#pragma unroll
    for (int mi = 0; mi < MR; ++mi)
#pragma unroll
      for (int ni = 0; ni < 4; ++ni)
#pragma unroll
        for (int kk = 0; kk < 2; ++kk)
          acc[mi][ni] = MFMA16(af[mi][kk], bfr[ni][kk], acc[mi][ni]);
  }

#pragma unroll
  for (int ni = 0; ni < 4; ++ni) {
    int gn = n0 + wc * 64 + ni * 16 + l15;
    float bv = bias[gn];
    if (MODE == 0) {
      int which = gn >> 10, rem = gn & 1023;
      int h = rem >> 6, dh = rem & 63;
#pragma unroll
      for (int mi = 0; mi < MR; ++mi) {
        int gmb = m0 + wr * (TM / 2) + mi * 16 + lg * 4;
#pragma unroll
        for (int r = 0; r < 4; ++r) {
          int gm = gmb + r;
          int b = gm >> 11, t = gm & 2047;
          float val = acc[mi][ni][r] + bv;
          size_t idx = ((size_t)((b * 16 + h) * 2048 + t)) * 64 + dh;
          if (which == 0) {
            q_bf[idx] = f2b(val * 0.18033688f);  // pre-scale by 1/sqrt(64)*log2(e)
          } else if (which == 1) {
            k_out[idx] = val;
            k_bf[idx] = f2b(val);
          } else {
            v_out[idx] = val;
            vt_bf[((size_t)(b * 16 + h) * 64 + dh) * 2048 + t] = f2b(val);
          }
        }
      }
    } else {
#pragma unroll
      for (int mi = 0; mi < MR; ++mi) {
        int gmb = m0 + wr * (TM / 2) + mi * 16 + lg * 4;
#pragma unroll
        for (int r = 0; r < 4; ++r)
          y_out[(size_t)(gmb + r) * N + gn] = acc[mi][ni][r] + bv;
      }
    }
  }
}

// ---------- causal flash attention: split-K, balanced round pairing ---------
// Piece rounds (round-robin dispatch puts u, u+256, u+512 on one CU):
//  round 0 (u 0..255):   first halves of qb 8..15   -> 16 tiles each
//  round 1 (u 256..511): second halves, qb ascending -> 2+2k tiles
//  round 2 (u 512..767): whole blocks, qb descending -> 16-2k tiles
// Every CU's triple sums to exactly 34 tiles (was 14..48 -> wall was paced
// by 48-tile CUs). Per-block behavior identical to the passing R17 kernel.
__global__ __launch_bounds__(256, 2) void attn_kernel(
    const unsigned short* __restrict__ qbuf, const unsigned short* __restrict__ kb,
    const unsigned short* __restrict__ vtb, unsigned short* __restrict__ y_att,
    unsigned short* __restrict__ part_o, float2* __restrict__ part_ml) {
  __shared__ __align__(16) char lds_k[3][8192];
  __shared__ __align__(16) char lds_v[3][8192];
  const int tid = threadIdx.x, lane = tid & 63, w = tid >> 6;
  const int u = (int)blockIdx.x;  // 0..767
  int bh, qb, t0, t1, half, isplit;
  if (u < 256) {                  // round 0: first halves (16 tiles)
    isplit = 1; half = 0;
    qb = 8 + (u >> 5); bh = u & 31;
    t0 = 0; t1 = 16;
  } else if (u < 512) {           // round 1: second halves, qb ascending
    int v = u - 256;
    isplit = 1; half = 1;
    qb = 8 + (v >> 5); bh = v & 31;
    t0 = 16; t1 = 2 * qb + 2;
  } else {                        // round 2: whole blocks, qb descending
    int s = u - 512;
    isplit = 0; half = 0;
    qb = 7 - (s >> 5); bh = s & 31;
    t0 = 0; t1 = 2 * qb + 2;
  }
  const int l31 = lane & 31, h = lane >> 5;
  const int qw0 = qb * 128 + w * 32;              // this wave's first q row
  const int qidx = qw0 + l31;
  const size_t base_off = (size_t)bh * (2048 * 64);
  const unsigned short* Q = qbuf + base_off;
  const char* Kb = (const char*)(kb + base_off);   // [2048][128B]
  const char* Vb = (const char*)(vtb + base_off);  // [64][4096B]
  const int my_last = (qw0 + 31) >> 6;  // last tile this wave computes

  int rowS[2], gcS[2];
#pragma unroll
  for (int j = 0; j < 2; ++j) {
    int L = tid * 16 + j * 4096;
    int row = L >> 7;
    rowS[j] = row;
    gcS[j] = (L & 127) ^ ((row & 7) << 4);
  }

#define STAGE(T, BUF)                                                           \
  if ((T) < t1) {                                                               \
    const int kv0_ = (T) * 64;                                                  \
    _Pragma("unroll") for (int j = 0; j < 2; ++j) {                             \
      gload16(Kb + (size_t)(kv0_ + rowS[j]) * 128 + gcS[j],                     \
              &lds_k[BUF][j * 4096 + tid * 16]);                                \
      gload16(Vb + (size_t)rowS[j] * 4096 + kv0_ * 2 + gcS[j],                  \
              &lds_v[BUF][j * 4096 + tid * 16]);                                \
    }                                                                           \
  }

  bf16x8 qB[4];
#pragma unroll
  for (int c = 0; c < 4; ++c)
    qB[c] = *(const bf16x8*)(Q + (size_t)(qw0 + l31) * 64 + c * 16 + h * 8);

  f32x16 yacc0 = {}, yacc1 = {};
  float m_run = -1e30f, l_run = 0.f;  // l_run is PER-LANE (half-row partial)
  const int swz = (l31 & 7) << 4;

  STAGE(t0, 0);
  STAGE(t0 + 1, 1);

  int rs = 0;  // (t - t0) % 3
  for (int t = t0; t < t1; ++t) {
    __syncthreads();  // drains stage(t+1) (issued a full iteration ago)
    const int wslot = rs < 1 ? rs + 2 : rs - 1;  // (t-t0+2)%3
    STAGE(t + 2, wslot);

    if (t <= my_last) {
      const char* Kl = lds_k[rs];
      const char* Vl = lds_v[rs];
      __builtin_amdgcn_s_setprio(1);
      f32x16 st0 = {}, st1 = {};
#pragma unroll
      for (int c = 0; c < 4; ++c) {
        bf16x8 k0 = *(const bf16x8*)(Kl + (size_t)l31 * 128 + ((c * 32 + h * 16) ^ swz));
        st0 = MFMA32(k0, qB[c], st0);
      }
#pragma unroll
      for (int c = 0; c < 4; ++c) {
        bf16x8 k1 = *(const bf16x8*)(Kl + (size_t)(32 + l31) * 128 + ((c * 32 + h * 16) ^ swz));
        st1 = MFMA32(k1, qB[c], st1);
      }
      __builtin_amdgcn_s_setprio(0);

      if (t == my_last) {  // diagonal tile: causal mask, in place
#pragma unroll
        for (int r = 0; r < 16; ++r) {
          int key0 = t * 64 + (r & 3) + 8 * ((r >> 2) & 3) + 4 * h;
          st0[r] = (key0 > qidx) ? -1e30f : st0[r];
          st1[r] = (key0 + 32 > qidx) ? -1e30f : st1[r];
        }
      }
      float mx;
      {
        float v[8];
#pragma unroll
        for (int r = 0; r < 8; ++r)
          v[r] = fmaxf(fmaxf(st0[r], st0[r + 8]), fmaxf(st1[r], st1[r + 8]));
        float a = fmaxf(fmaxf(v[0], v[1]), v[2]);
        float b = fmaxf(fmaxf(v[3], v[4]), v[5]);
        float c = fmaxf(v[6], v[7]);
        mx = fmaxf(fmaxf(a, b), c);
      }
      mx = fmaxf(mx, __shfl_xor(mx, 32));  // cross-half row max
      if (__any(mx > m_run + 8.f)) {  // defer-max
        float mnew = fmaxf(m_run, mx);
        float alpha = exp2f(m_run - mnew);
#pragma unroll
        for (int r = 0; r < 16; ++r) { yacc0[r] *= alpha; yacc1[r] *= alpha; }
        l_run *= alpha;
        m_run = mnew;
      }
      float ls = 0.f;
#pragma unroll
      for (int r = 0; r < 16; ++r) {
        st0[r] = exp2f(st0[r] - m_run);
        ls += st0[r];
      }
#pragma unroll
      for (int r = 0; r < 16; ++r) {
        st1[r] = exp2f(st1[r] - m_run);
        ls += st1[r];
      }
      l_run += ls;  // per-lane; merged across halves after the loop

      U8 pf[4];
      {
        unsigned pk0 = cvtpk(st0[0], st0[1]), pk1 = cvtpk(st0[2], st0[3]);
        unsigned pk2 = cvtpk(st0[4], st0[5]), pk3 = cvtpk(st0[6], st0[7]);
        unsigned pk4 = cvtpk(st0[8], st0[9]), pk5 = cvtpk(st0[10], st0[11]);
        unsigned pk6 = cvtpk(st0[12], st0[13]), pk7 = cvtpk(st0[14], st0[15]);
        swap32(pk0, pk2); swap32(pk1, pk3); swap32(pk4, pk6); swap32(pk5, pk7);
        pf[0].u[0] = pk0; pf[0].u[1] = pk1; pf[0].u[2] = pk2; pf[0].u[3] = pk3;
        pf[1].u[0] = pk4; pf[1].u[1] = pk5; pf[1].u[2] = pk6; pf[1].u[3] = pk7;
        unsigned qk0 = cvtpk(st1[0], st1[1]), qk1 = cvtpk(st1[2], st1[3]);
        unsigned qk2 = cvtpk(st1[4], st1[5]), qk3 = cvtpk(st1[6], st1[7]);
        unsigned qk4 = cvtpk(st1[8], st1[9]), qk5 = cvtpk(st1[10], st1[11]);
        unsigned qk6 = cvtpk(st1[12], st1[13]), qk7 = cvtpk(st1[14], st1[15]);
        swap32(qk0, qk2); swap32(qk1, qk3); swap32(qk4, qk6); swap32(qk5, qk7);
        pf[2].u[0] = qk0; pf[2].u[1] = qk1; pf[2].u[2] = qk2; pf[2].u[3] = qk3;
        pf[3].u[0] = qk4; pf[3].u[1] = qk5; pf[3].u[2] = qk6; pf[3].u[3] = qk7;
      }

      __builtin_amdgcn_s_setprio(1);
#pragma unroll
      for (int c = 0; c < 4; ++c) {
        bf16x8 v0 = *(const bf16x8*)(Vl + (size_t)l31 * 128 + ((c * 32 + h * 16) ^ swz));
        yacc0 = MFMA32(v0, pf[c].v, yacc0);
      }
#pragma unroll
      for (int c = 0; c < 4; ++c) {
        bf16x8 v1 = *(const bf16x8*)(Vl + (size_t)(32 + l31) * 128 + ((c * 32 + h * 16) ^ swz));
        yacc1 = MFMA32(v1, pf[c].v, yacc1);
      }
      __builtin_amdgcn_s_setprio(0);
    }
    rs = rs < 2 ? rs + 1 : 0;
  }
#undef STAGE

  float l_tot = l_run + __shfl_xor(l_run, 32);
  float inv = 1.f / l_tot;
  if (!isplit) {
    const int b = bh >> 4, head = bh & 15;
    size_t rowb = ((size_t)(b * 2048 + qw0 + l31) * 16 + head) * 64;
#pragma unroll
    for (int rg = 0; rg < 4; ++rg) {
      int d0 = 8 * rg + 4 * h;
      ushort4 o0, o1;
      o0.x = f2b(yacc0[4 * rg + 0] * inv);
      o0.y = f2b(yacc0[4 * rg + 1] * inv);
      o0.z = f2b(yacc0[4 * rg + 2] * inv);
      o0.w = f2b(yacc0[4 * rg + 3] * inv);
      *(ushort4*)(y_att + rowb + d0) = o0;
      o1.x = f2b(yacc1[4 * rg + 0] * inv);
      o1.y = f2b(yacc1[4 * rg + 1] * inv);
      o1.z = f2b(yacc1[4 * rg + 2] * inv);
      o1.w = f2b(yacc1[4 * rg + 3] * inv);
      *(ushort4*)(y_att + rowb + 32 + d0) = o1;
    }
  } else {
    const int p = ((15 - qb) << 5) | bh;  // 0..255
    unsigned short* po = part_o + (size_t)(p * 2 + half) * 8192;
    const int lrow = w * 32 + l31;
    size_t rowb = (size_t)lrow * 64;
#pragma unroll
    for (int rg = 0; rg < 4; ++rg) {
      int d0 = 8 * rg + 4 * h;
      ushort4 o0, o1;
      o0.x = f2b(yacc0[4 * rg + 0] * inv);
      o0.y = f2b(yacc0[4 * rg + 1] * inv);
      o0.z = f2b(yacc0[4 * rg + 2] * inv);
      o0.w = f2b(yacc0[4 * rg + 3] * inv);
      *(ushort4*)(po + rowb + d0) = o0;
      o1.x = f2b(yacc1[4 * rg + 0] * inv);
      o1.y = f2b(yacc1[4 * rg + 1] * inv);
      o1.z = f2b(yacc1[4 * rg + 2] * inv);
      o1.w = f2b(yacc1[4 * rg + 3] * inv);
      *(ushort4*)(po + rowb + 32 + d0) = o1;
    }
    if (h == 0) part_ml[(p * 2 + half) * 128 + lrow] = make_float2(m_run, l_tot);
  }
}

// ---------- merge the two KV-halves of each split output block ----------
__global__ __launch_bounds__(256) void attn_merge_kernel(
    const unsigned short* __restrict__ part_o, const float2* __restrict__ part_ml,
    unsigned short* __restrict__ y_att) {
  const int p = (int)blockIdx.x;  // 0..255
  const int qb = 15 - (p >> 5);
  const int bh = p & 31;
  const int tid = threadIdx.x;
  const int r = tid >> 1;           // 0..127
  const int c0 = (tid & 1) << 5;    // 0 or 32
  const unsigned short* o0 = part_o + (size_t)(p * 2 + 0) * 8192 + r * 64 + c0;
  const unsigned short* o1 = part_o + (size_t)(p * 2 + 1) * 8192 + r * 64 + c0;
  float2 ml0 = part_ml[(p * 2 + 0) * 128 + r];
  float2 ml1 = part_ml[(p * 2 + 1) * 128 + r];
  float mn = fmaxf(ml0.x, ml1.x);
  float w0 = ml0.y * exp2f(ml0.x - mn);
  float w1 = ml1.y * exp2f(ml1.x - mn);
  float inv = 1.f / (w0 + w1);
  w0 *= inv;
  w1 *= inv;
  const int b = bh >> 4, head = bh & 15;
  unsigned short* dst =
      y_att + ((size_t)(b * 2048 + qb * 128 + r) * 16 + head) * 64 + c0;
#pragma unroll
  for (int c = 0; c < 32; c += 4) {
    ushort4 a = *(const ushort4*)(o0 + c);
    ushort4 bb = *(const ushort4*)(o1 + c);
    ushort4 o;
    o.x = f2b(w0 * b2f(a.x) + w1 * b2f(bb.x));
    o.y = f2b(w0 * b2f(a.y) + w1 * b2f(bb.y));
    o.z = f2b(w0 * b2f(a.z) + w1 * b2f(bb.z));
    o.w = f2b(w0 * b2f(a.w) + w1 * b2f(bb.w));
    *(ushort4*)(dst + c) = o;
  }
}

// ---------- launcher ----------
extern "C" void kernel_launch(void* const* d_in, const int* in_sizes, int n_in,
                              void* d_out, int out_size, void* d_ws, size_t ws_size,
                              hipStream_t stream) {
  const float* x = (const float*)d_in[0];
  const float* W_qkv = (const float*)d_in[1];
  const float* b_qkv = (const float*)d_in[2];
  const float* W_out = (const float*)d_in[3];
  const float* b_out = (const float*)d_in[4];

  float* y_out = (float*)d_out;                 // [2,2048,1024]
  float* k_out = y_out + 4194304;               // [2,16,2048,64]
  float* v_out = y_out + 8388608;               // [2,16,2048,64]

  unsigned short* x_bf = (unsigned short*)d_ws;       // [4096,1024]
  unsigned short* wqkv_t = x_bf + 4194304;            // [3072,1024]
  unsigned short* wout_t = wqkv_t + 3145728;          // [1024,1024]
  unsigned short* q_bf = wout_t + 1048576;            // [B,H,T,Dh] (pre-scaled)
  unsigned short* k_bf = q_bf + 4194304;              // [B,H,T,Dh]
  unsigned short* vt_bf = k_bf + 4194304;             // [B,H,Dh,T]
  unsigned short* y_att = vt_bf + 4194304;            // [B,T,H*Dh]

  // attn partial buffers: reuse regions dead after GEMM0 (x_bf, wqkv_t)
  unsigned short* part_o = x_bf;                 // 512 x 8192 ushort = 8 MB
  float2* part_ml = (float2*)wqkv_t;             // 512 x 128 float2 = 512 KB

  prepass_kernel<<<5120, 1024, 0, stream>>>(x, x_bf, W_qkv, wqkv_t, W_out, wout_t);
  gemm_bf16_kernel<0, 128><<<dim3(24, 32), 256, 0, stream>>>(
      x_bf, wqkv_t, b_qkv, 4096, 3072, 1024, q_bf, k_bf, vt_bf, k_out, v_out, nullptr);
  attn_kernel<<<768, 256, 0, stream>>>(q_bf, k_bf, vt_bf, y_att, part_o, part_ml);
  attn_merge_kernel<<<256, 256, 0, stream>>>(part_o, part_ml, y_att);
  gemm_bf16_kernel<1, 64><<<dim3(8, 64), 256, 0, stream>>>(
      y_att, wout_t, b_out, 4096, 1024, 1024, nullptr, nullptr, nullptr, nullptr, nullptr, y_out);
}

// Round 19
// 115.199 us; speedup vs baseline: 1.2438x; 1.0061x over previous
//
#include <hip/hip_runtime.h>

// ---------- types ----------
typedef __attribute__((ext_vector_type(8))) short bf16x8;   // 8 bf16 = 4 VGPR
typedef __attribute__((ext_vector_type(4))) float f32x4;
typedef __attribute__((ext_vector_type(16))) float f32x16;

#define MFMA16(A, B, C) __builtin_amdgcn_mfma_f32_16x16x32_bf16((A), (B), (C), 0, 0, 0)
#define MFMA32(A, B, C) __builtin_amdgcn_mfma_f32_32x32x16_bf16((A), (B), (C), 0, 0, 0)

union U8 { unsigned u[4]; bf16x8 v; };

// fp32 -> bf16 (round-to-nearest-even), header-independent
__device__ __forceinline__ unsigned short f2b(float f) {
  unsigned u = __builtin_bit_cast(unsigned, f);
  unsigned r = (u + 0x7fffu + ((u >> 16) & 1u)) >> 16;
  return (unsigned short)r;
}
__device__ __forceinline__ float b2f(unsigned short u) {
  unsigned v = ((unsigned)u) << 16;
  return __builtin_bit_cast(float, v);
}

// packed f32x2 -> bf16x2
__device__ __forceinline__ unsigned cvtpk(float lo, float hi) {
  unsigned r;
  asm("v_cvt_pk_bf16_f32 %0, %1, %2" : "=v"(r) : "v"(lo), "v"(hi));
  return r;
}
// exchange a.hi-half <-> b.lo-half across lane32 boundary.
// NOTE: operands MUST be distinct values — identical inputs get coalesced
// into one VGPR and the swap corrupts the reduction (R13 NaN bug).
__device__ __forceinline__ void swap32(unsigned& a, unsigned& b) {
  asm("v_permlane32_swap_b32 %0, %1" : "+v"(a), "+v"(b));
}

// async global->LDS, 16B per lane. dest = wave-uniform base + lane*16
__device__ __forceinline__ void gload16(const void* g, void* l) {
  __builtin_amdgcn_global_load_lds(
      (const __attribute__((address_space(1))) void*)g,
      (__attribute__((address_space(3))) void*)l, 16, 0, 0);
}

// ---------- fused pre-pass: x->bf16 copy + both weight transposes ----------
__global__ __launch_bounds__(1024) void prepass_kernel(
    const float* __restrict__ x, unsigned short* __restrict__ x_bf,
    const float* __restrict__ s1, unsigned short* __restrict__ d1,
    const float* __restrict__ s2, unsigned short* __restrict__ d2) {
  __shared__ unsigned short t[32][33];
  const int bid = (int)blockIdx.x, tid = threadIdx.x;
  if (bid < 1024) {
    int i = (bid * 1024 + tid) * 4;
    float4 v = *(const float4*)(x + i);
    ushort4 o;
    o.x = f2b(v.x); o.y = f2b(v.y); o.z = f2b(v.z); o.w = f2b(v.w);
    *(ushort4*)(x_bf + i) = o;
    return;
  }
  int b = bid - 1024;
  int bx = b & 127, by = b >> 7;  // bx: col tile, by: row tile
  const float* src;
  unsigned short* dst;
  int C;
  if (bx < 96) { src = s1; dst = d1; C = 3072; }
  else         { src = s2; dst = d2; C = 1024; bx -= 96; }
  int xx = tid & 31, yy = tid >> 5;
  int c0 = bx * 32, r0 = by * 32;
  t[yy][xx] = f2b(src[(size_t)(r0 + yy) * C + c0 + xx]);
  __syncthreads();
  dst[(size_t)(c0 + yy) * 1024 + r0 + xx] = t[xx][yy];
}

// ---------- GEMM: C[M,N] = A[M,K] * Bt[N,K]^T (+bias), bf16 MFMA ----------
// R14-exact structure (single buffer, 2 barriers/K-step — both double-buffer
// variants regressed). TM=128 for MODE0 (3 blocks/CU), TM=64 for MODE1
// (512 blocks = 2 blocks/CU).
template <int MODE, int TM>
__global__ __launch_bounds__(256, 2) void gemm_bf16_kernel(
    const unsigned short* __restrict__ A, const unsigned short* __restrict__ Bt,
    const float* __restrict__ bias, int M, int N, int K,
    unsigned short* __restrict__ q_bf, unsigned short* __restrict__ k_bf,
    unsigned short* __restrict__ vt_bf, float* __restrict__ k_out,
    float* __restrict__ v_out, float* __restrict__ y_out) {
  constexpr int MR = TM / 32;       // A-fragment rows per wave / stage chunks
  __shared__ __align__(16) unsigned short As[TM * 64];
  __shared__ __align__(16) unsigned short Bs[128 * 64];
  const int tid = threadIdx.x;
  const int lane = tid & 63, wid = tid >> 6;
  const int wr = wid >> 1, wc = wid & 1;
  const int l15 = lane & 15, lg = lane >> 4;
  const int m0 = blockIdx.y * TM, n0 = blockIdx.x * 128;

  f32x4 acc[MR][4] = {};

  int rowS[4], colS[4];
#pragma unroll
  for (int j = 0; j < 4; ++j) {
    int L = j * 4096 + tid * 16;  // linear LDS byte
    int row = L >> 7;
    int c = (L & 127) ^ ((row & 7) << 4);
    rowS[j] = row;
    colS[j] = c >> 1;  // bf16 elements
  }

  for (int kt = 0; kt < K; kt += 64) {
    __syncthreads();
#pragma unroll
    for (int j = 0; j < MR; ++j)
      gload16(A + (size_t)(m0 + rowS[j]) * K + kt + colS[j],
              (char*)As + j * 4096 + tid * 16);
#pragma unroll
    for (int j = 0; j < 4; ++j)
      gload16(Bt + (size_t)(n0 + rowS[j]) * K + kt + colS[j],
              (char*)Bs + j * 4096 + tid * 16);
    __syncthreads();

    bf16x8 af[MR][2], bfr[4][2];
#pragma unroll
    for (int i = 0; i < MR; ++i)
#pragma unroll
      for (int kk = 0; kk < 2; ++kk) {
        int ra = wr * (TM / 2) + i * 16 + l15;
        int cb = kk * 64 + lg * 16;
        af[i][kk] = *(const bf16x8*)((const char*)As + ra * 128 + (cb ^ ((ra & 7) << 4)));
      }
#pragma unroll
    for (int i = 0; i < 4; ++i)
#pragma unroll
      for (int kk = 0; kk < 2; ++kk) {
        int rb = wc * 64 + i * 16 + l15;
        int cb = kk * 64 + lg * 16;
        bfr[i][kk] = *(const bf16x8*)((const char*)Bs + rb * 128 + (cb ^ ((rb & 7) << 4)));
      }
#pragma unroll
    for (int mi = 0; mi < MR; ++mi)
#pragma unroll
      for (int ni = 0; ni < 4; ++ni)
#pragma unroll
        for (int kk = 0; kk < 2; ++kk)
          acc[mi][ni] = MFMA16(af[mi][kk], bfr[ni][kk], acc[mi][ni]);
  }

#pragma unroll
  for (int ni = 0; ni < 4; ++ni) {
    int gn = n0 + wc * 64 + ni * 16 + l15;
    float bv = bias[gn];
    if (MODE == 0) {
      int which = gn >> 10, rem = gn & 1023;
      int h = rem >> 6, dh = rem & 63;
#pragma unroll
      for (int mi = 0; mi < MR; ++mi) {
        int gmb = m0 + wr * (TM / 2) + mi * 16 + lg * 4;
#pragma unroll
        for (int r = 0; r < 4; ++r) {
          int gm = gmb + r;
          int b = gm >> 11, t = gm & 2047;
          float val = acc[mi][ni][r] + bv;
          size_t idx = ((size_t)((b * 16 + h) * 2048 + t)) * 64 + dh;
          if (which == 0) {
            q_bf[idx] = f2b(val * 0.18033688f);  // pre-scale by 1/sqrt(64)*log2(e)
          } else if (which == 1) {
            k_out[idx] = val;
            k_bf[idx] = f2b(val);
          } else {
            v_out[idx] = val;
            vt_bf[((size_t)(b * 16 + h) * 64 + dh) * 2048 + t] = f2b(val);
          }
        }
      }
    } else {
#pragma unroll
      for (int mi = 0; mi < MR; ++mi) {
        int gmb = m0 + wr * (TM / 2) + mi * 16 + lg * 4;
#pragma unroll
        for (int r = 0; r < 4; ++r)
          y_out[(size_t)(gmb + r) * N + gn] = acc[mi][ni][r] + bv;
      }
    }
  }
}

// ---------- causal flash attention: split-K, balanced rounds, dbuf ----------
// Balanced round pairing (R18): every CU's three blocks sum to 34 tiles.
// Double buffer (32KB LDS) + __launch_bounds__(256,3): 3 blocks/CU resident
// (whole 768-block grid co-resident), one more independent dep chain per
// SIMD. Sync protocol unchanged in distance: the sync at top of iteration t
// drains stage(t) issued one full iteration earlier; STAGE(t+1) after the
// sync overwrites the buffer compute(t-1) just finished reading (barrier
// closes the WAR).
__global__ __launch_bounds__(256, 3) void attn_kernel(
    const unsigned short* __restrict__ qbuf, const unsigned short* __restrict__ kb,
    const unsigned short* __restrict__ vtb, unsigned short* __restrict__ y_att,
    unsigned short* __restrict__ part_o, float2* __restrict__ part_ml) {
  __shared__ __align__(16) char lds_k[2][8192];
  __shared__ __align__(16) char lds_v[2][8192];
  const int tid = threadIdx.x, lane = tid & 63, w = tid >> 6;
  const int u = (int)blockIdx.x;  // 0..767
  int bh, qb, t0, t1, half, isplit;
  if (u < 256) {                  // round 0: first halves (16 tiles)
    isplit = 1; half = 0;
    qb = 8 + (u >> 5); bh = u & 31;
    t0 = 0; t1 = 16;
  } else if (u < 512) {           // round 1: second halves, qb ascending
    int v = u - 256;
    isplit = 1; half = 1;
    qb = 8 + (v >> 5); bh = v & 31;
    t0 = 16; t1 = 2 * qb + 2;
  } else {                        // round 2: whole blocks, qb descending
    int s = u - 512;
    isplit = 0; half = 0;
    qb = 7 - (s >> 5); bh = s & 31;
    t0 = 0; t1 = 2 * qb + 2;
  }
  const int l31 = lane & 31, h = lane >> 5;
  const int qw0 = qb * 128 + w * 32;              // this wave's first q row
  const int qidx = qw0 + l31;
  const size_t base_off = (size_t)bh * (2048 * 64);
  const unsigned short* Q = qbuf + base_off;
  const char* Kb = (const char*)(kb + base_off);   // [2048][128B]
  const char* Vb = (const char*)(vtb + base_off);  // [64][4096B]
  const int my_last = (qw0 + 31) >> 6;  // last tile this wave computes

  int rowS[2], gcS[2];
#pragma unroll
  for (int j = 0; j < 2; ++j) {
    int L = tid * 16 + j * 4096;
    int row = L >> 7;
    rowS[j] = row;
    gcS[j] = (L & 127) ^ ((row & 7) << 4);
  }

#define STAGE(T)                                                                \
  if ((T) < t1) {                                                               \
    const int kv0_ = (T) * 64;                                                  \
    const int buf_ = (T) & 1;                                                   \
    _Pragma("unroll") for (int j = 0; j < 2; ++j) {                             \
      gload16(Kb + (size_t)(kv0_ + rowS[j]) * 128 + gcS[j],                     \
              &lds_k[buf_][j * 4096 + tid * 16]);                               \
      gload16(Vb + (size_t)rowS[j] * 4096 + kv0_ * 2 + gcS[j],                  \
              &lds_v[buf_][j * 4096 + tid * 16]);                               \
    }                                                                           \
  }

  bf16x8 qB[4];
#pragma unroll
  for (int c = 0; c < 4; ++c)
    qB[c] = *(const bf16x8*)(Q + (size_t)(qw0 + l31) * 64 + c * 16 + h * 8);

  f32x16 yacc0 = {}, yacc1 = {};
  float m_run = -1e30f, l_run = 0.f;  // l_run is PER-LANE (half-row partial)
  const int swz = (l31 & 7) << 4;

  STAGE(t0);

  for (int t = t0; t < t1; ++t) {
    __syncthreads();  // drains stage(t) (issued a full iteration ago)
    STAGE(t + 1);

    if (t <= my_last) {
      const char* Kl = lds_k[t & 1];
      const char* Vl = lds_v[t & 1];
      __builtin_amdgcn_s_setprio(1);
      f32x16 st0 = {}, st1 = {};
#pragma unroll
      for (int c = 0; c < 4; ++c) {
        bf16x8 k0 = *(const bf16x8*)(Kl + (size_t)l31 * 128 + ((c * 32 + h * 16) ^ swz));
        st0 = MFMA32(k0, qB[c], st0);
      }
#pragma unroll
      for (int c = 0; c < 4; ++c) {
        bf16x8 k1 = *(const bf16x8*)(Kl + (size_t)(32 + l31) * 128 + ((c * 32 + h * 16) ^ swz));
        st1 = MFMA32(k1, qB[c], st1);
      }
      __builtin_amdgcn_s_setprio(0);

      if (t == my_last) {  // diagonal tile: causal mask, in place
#pragma unroll
        for (int r = 0; r < 16; ++r) {
          int key0 = t * 64 + (r & 3) + 8 * ((r >> 2) & 3) + 4 * h;
          st0[r] = (key0 > qidx) ? -1e30f : st0[r];
          st1[r] = (key0 + 32 > qidx) ? -1e30f : st1[r];
        }
      }
      float mx;
      {
        float v[8];
#pragma unroll
        for (int r = 0; r < 8; ++r)
          v[r] = fmaxf(fmaxf(st0[r], st0[r + 8]), fmaxf(st1[r], st1[r + 8]));
        float a = fmaxf(fmaxf(v[0], v[1]), v[2]);
        float b = fmaxf(fmaxf(v[3], v[4]), v[5]);
        float c = fmaxf(v[6], v[7]);
        mx = fmaxf(fmaxf(a, b), c);
      }
      mx = fmaxf(mx, __shfl_xor(mx, 32));  // cross-half row max
      if (__any(mx > m_run + 8.f)) {  // defer-max
        float mnew = fmaxf(m_run, mx);
        float alpha = exp2f(m_run - mnew);
#pragma unroll
        for (int r = 0; r < 16; ++r) { yacc0[r] *= alpha; yacc1[r] *= alpha; }
        l_run *= alpha;
        m_run = mnew;
      }
      float ls = 0.f;
#pragma unroll
      for (int r = 0; r < 16; ++r) {
        st0[r] = exp2f(st0[r] - m_run);
        ls += st0[r];
      }
#pragma unroll
      for (int r = 0; r < 16; ++r) {
        st1[r] = exp2f(st1[r] - m_run);
        ls += st1[r];
      }
      l_run += ls;  // per-lane; merged across halves after the loop

      U8 pf[4];
      {
        unsigned pk0 = cvtpk(st0[0], st0[1]), pk1 = cvtpk(st0[2], st0[3]);
        unsigned pk2 = cvtpk(st0[4], st0[5]), pk3 = cvtpk(st0[6], st0[7]);
        unsigned pk4 = cvtpk(st0[8], st0[9]), pk5 = cvtpk(st0[10], st0[11]);
        unsigned pk6 = cvtpk(st0[12], st0[13]), pk7 = cvtpk(st0[14], st0[15]);
        swap32(pk0, pk2); swap32(pk1, pk3); swap32(pk4, pk6); swap32(pk5, pk7);
        pf[0].u[0] = pk0; pf[0].u[1] = pk1; pf[0].u[2] = pk2; pf[0].u[3] = pk3;
        pf[1].u[0] = pk4; pf[1].u[1] = pk5; pf[1].u[2] = pk6; pf[1].u[3] = pk7;
        unsigned qk0 = cvtpk(st1[0], st1[1]), qk1 = cvtpk(st1[2], st1[3]);
        unsigned qk2 = cvtpk(st1[4], st1[5]), qk3 = cvtpk(st1[6], st1[7]);
        unsigned qk4 = cvtpk(st1[8], st1[9]), qk5 = cvtpk(st1[10], st1[11]);
        unsigned qk6 = cvtpk(st1[12], st1[13]), qk7 = cvtpk(st1[14], st1[15]);
        swap32(qk0, qk2); swap32(qk1, qk3); swap32(qk4, qk6); swap32(qk5, qk7);
        pf[2].u[0] = qk0; pf[2].u[1] = qk1; pf[2].u[2] = qk2; pf[2].u[3] = qk3;
        pf[3].u[0] = qk4; pf[3].u[1] = qk5; pf[3].u[2] = qk6; pf[3].u[3] = qk7;
      }

      __builtin_amdgcn_s_setprio(1);
#pragma unroll
      for (int c = 0; c < 4; ++c) {
        bf16x8 v0 = *(const bf16x8*)(Vl + (size_t)l31 * 128 + ((c * 32 + h * 16) ^ swz));
        yacc0 = MFMA32(v0, pf[c].v, yacc0);
      }
#pragma unroll
      for (int c = 0; c < 4; ++c) {
        bf16x8 v1 = *(const bf16x8*)(Vl + (size_t)(32 + l31) * 128 + ((c * 32 + h * 16) ^ swz));
        yacc1 = MFMA32(v1, pf[c].v, yacc1);
      }
      __builtin_amdgcn_s_setprio(0);
    }
  }
#undef STAGE

  float l_tot = l_run + __shfl_xor(l_run, 32);
  float inv = 1.f / l_tot;
  if (!isplit) {
    const int b = bh >> 4, head = bh & 15;
    size_t rowb = ((size_t)(b * 2048 + qw0 + l31) * 16 + head) * 64;
#pragma unroll
    for (int rg = 0; rg < 4; ++rg) {
      int d0 = 8 * rg + 4 * h;
      ushort4 o0, o1;
      o0.x = f2b(yacc0[4 * rg + 0] * inv);
      o0.y = f2b(yacc0[4 * rg + 1] * inv);
      o0.z = f2b(yacc0[4 * rg + 2] * inv);
      o0.w = f2b(yacc0[4 * rg + 3] * inv);
      *(ushort4*)(y_att + rowb + d0) = o0;
      o1.x = f2b(yacc1[4 * rg + 0] * inv);
      o1.y = f2b(yacc1[4 * rg + 1] * inv);
      o1.z = f2b(yacc1[4 * rg + 2] * inv);
      o1.w = f2b(yacc1[4 * rg + 3] * inv);
      *(ushort4*)(y_att + rowb + 32 + d0) = o1;
    }
  } else {
    const int p = ((15 - qb) << 5) | bh;  // 0..255
    unsigned short* po = part_o + (size_t)(p * 2 + half) * 8192;
    const int lrow = w * 32 + l31;
    size_t rowb = (size_t)lrow * 64;
#pragma unroll
    for (int rg = 0; rg < 4; ++rg) {
      int d0 = 8 * rg + 4 * h;
      ushort4 o0, o1;
      o0.x = f2b(yacc0[4 * rg + 0] * inv);
      o0.y = f2b(yacc0[4 * rg + 1] * inv);
      o0.z = f2b(yacc0[4 * rg + 2] * inv);
      o0.w = f2b(yacc0[4 * rg + 3] * inv);
      *(ushort4*)(po + rowb + d0) = o0;
      o1.x = f2b(yacc1[4 * rg + 0] * inv);
      o1.y = f2b(yacc1[4 * rg + 1] * inv);
      o1.z = f2b(yacc1[4 * rg + 2] * inv);
      o1.w = f2b(yacc1[4 * rg + 3] * inv);
      *(ushort4*)(po + rowb + 32 + d0) = o1;
    }
    if (h == 0) part_ml[(p * 2 + half) * 128 + lrow] = make_float2(m_run, l_tot);
  }
}

// ---------- merge the two KV-halves of each split output block ----------
__global__ __launch_bounds__(256) void attn_merge_kernel(
    const unsigned short* __restrict__ part_o, const float2* __restrict__ part_ml,
    unsigned short* __restrict__ y_att) {
  const int p = (int)blockIdx.x;  // 0..255
  const int qb = 15 - (p >> 5);
  const int bh = p & 31;
  const int tid = threadIdx.x;
  const int r = tid >> 1;           // 0..127
  const int c0 = (tid & 1) << 5;    // 0 or 32
  const unsigned short* o0 = part_o + (size_t)(p * 2 + 0) * 8192 + r * 64 + c0;
  const unsigned short* o1 = part_o + (size_t)(p * 2 + 1) * 8192 + r * 64 + c0;
  float2 ml0 = part_ml[(p * 2 + 0) * 128 + r];
  float2 ml1 = part_ml[(p * 2 + 1) * 128 + r];
  float mn = fmaxf(ml0.x, ml1.x);
  float w0 = ml0.y * exp2f(ml0.x - mn);
  float w1 = ml1.y * exp2f(ml1.x - mn);
  float inv = 1.f / (w0 + w1);
  w0 *= inv;
  w1 *= inv;
  const int b = bh >> 4, head = bh & 15;
  unsigned short* dst =
      y_att + ((size_t)(b * 2048 + qb * 128 + r) * 16 + head) * 64 + c0;
#pragma unroll
  for (int c = 0; c < 32; c += 4) {
    ushort4 a = *(const ushort4*)(o0 + c);
    ushort4 bb = *(const ushort4*)(o1 + c);
    ushort4 o;
    o.x = f2b(w0 * b2f(a.x) + w1 * b2f(bb.x));
    o.y = f2b(w0 * b2f(a.y) + w1 * b2f(bb.y));
    o.z = f2b(w0 * b2f(a.z) + w1 * b2f(bb.z));
    o.w = f2b(w0 * b2f(a.w) + w1 * b2f(bb.w));
    *(ushort4*)(dst + c) = o;
  }
}

// ---------- launcher ----------
extern "C" void kernel_launch(void* const* d_in, const int* in_sizes, int n_in,
                              void* d_out, int out_size, void* d_ws, size_t ws_size,
                              hipStream_t stream) {
  const float* x = (const float*)d_in[0];
  const float* W_qkv = (const float*)d_in[1];
  const float* b_qkv = (const float*)d_in[2];
  const float* W_out = (const float*)d_in[3];
  const float* b_out = (const float*)d_in[4];

  float* y_out = (float*)d_out;                 // [2,2048,1024]
  float* k_out = y_out + 4194304;               // [2,16,2048,64]
  float* v_out = y_out + 8388608;               // [2,16,2048,64]

  unsigned short* x_bf = (unsigned short*)d_ws;       // [4096,1024]
  unsigned short* wqkv_t = x_bf + 4194304;            // [3072,1024]
  unsigned short* wout_t = wqkv_t + 3145728;          // [1024,1024]
  unsigned short* q_bf = wout_t + 1048576;            // [B,H,T,Dh] (pre-scaled)
  unsigned short* k_bf = q_bf + 4194304;              // [B,H,T,Dh]
  unsigned short* vt_bf = k_bf + 4194304;             // [B,H,Dh,T]
  unsigned short* y_att = vt_bf + 4194304;            // [B,T,H*Dh]

  // attn partial buffers: reuse regions dead after GEMM0 (x_bf, wqkv_t)
  unsigned short* part_o = x_bf;                 // 512 x 8192 ushort = 8 MB
  float2* part_ml = (float2*)wqkv_t;             // 512 x 128 float2 = 512 KB

  prepass_kernel<<<5120, 1024, 0, stream>>>(x, x_bf, W_qkv, wqkv_t, W_out, wout_t);
  gemm_bf16_kernel<0, 128><<<dim3(24, 32), 256, 0, stream>>>(
      x_bf, wqkv_t, b_qkv, 4096, 3072, 1024, q_bf, k_bf, vt_bf, k_out, v_out, nullptr);
  attn_kernel<<<768, 256, 0, stream>>>(q_bf, k_bf, vt_bf, y_att, part_o, part_ml);
  attn_merge_kernel<<<256, 256, 0, stream>>>(part_o, part_ml, y_att);
  gemm_bf16_kernel<1, 64><<<dim3(8, 64), 256, 0, stream>>>(
      y_att, wout_t, b_out, 4096, 1024, 1024, nullptr, nullptr, nullptr, nullptr, nullptr, y_out);
}

// Round 20
// 113.430 us; speedup vs baseline: 1.2632x; 1.0156x over previous
//
#include <hip/hip_runtime.h>

// ---------- types ----------
typedef __attribute__((ext_vector_type(8))) short bf16x8;   // 8 bf16 = 4 VGPR
typedef __attribute__((ext_vector_type(4))) float f32x4;
typedef __attribute__((ext_vector_type(16))) float f32x16;

#define MFMA16(A, B, C) __builtin_amdgcn_mfma_f32_16x16x32_bf16((A), (B), (C), 0, 0, 0)
#define MFMA32(A, B, C) __builtin_amdgcn_mfma_f32_32x32x16_bf16((A), (B), (C), 0, 0, 0)

union U8 { unsigned u[4]; bf16x8 v; };

// fp32 -> bf16 (round-to-nearest-even), header-independent
__device__ __forceinline__ unsigned short f2b(float f) {
  unsigned u = __builtin_bit_cast(unsigned, f);
  unsigned r = (u + 0x7fffu + ((u >> 16) & 1u)) >> 16;
  return (unsigned short)r;
}
__device__ __forceinline__ float b2f(unsigned short u) {
  unsigned v = ((unsigned)u) << 16;
  return __builtin_bit_cast(float, v);
}

// packed f32x2 -> bf16x2
__device__ __forceinline__ unsigned cvtpk(float lo, float hi) {
  unsigned r;
  asm("v_cvt_pk_bf16_f32 %0, %1, %2" : "=v"(r) : "v"(lo), "v"(hi));
  return r;
}
// exchange a.hi-half <-> b.lo-half across lane32 boundary.
// NOTE: operands MUST be distinct values — identical inputs get coalesced
// into one VGPR and the swap corrupts the reduction (R13 NaN bug).
__device__ __forceinline__ void swap32(unsigned& a, unsigned& b) {
  asm("v_permlane32_swap_b32 %0, %1" : "+v"(a), "+v"(b));
}

// async global->LDS, 16B per lane. dest = wave-uniform base + lane*16
__device__ __forceinline__ void gload16(const void* g, void* l) {
  __builtin_amdgcn_global_load_lds(
      (const __attribute__((address_space(1))) void*)g,
      (__attribute__((address_space(3))) void*)l, 16, 0, 0);
}

// ---------- fused pre-pass: x->bf16 copy + both weight transposes ----------
__global__ __launch_bounds__(1024) void prepass_kernel(
    const float* __restrict__ x, unsigned short* __restrict__ x_bf,
    const float* __restrict__ s1, unsigned short* __restrict__ d1,
    const float* __restrict__ s2, unsigned short* __restrict__ d2) {
  __shared__ unsigned short t[32][33];
  const int bid = (int)blockIdx.x, tid = threadIdx.x;
  if (bid < 1024) {
    int i = (bid * 1024 + tid) * 4;
    float4 v = *(const float4*)(x + i);
    ushort4 o;
    o.x = f2b(v.x); o.y = f2b(v.y); o.z = f2b(v.z); o.w = f2b(v.w);
    *(ushort4*)(x_bf + i) = o;
    return;
  }
  int b = bid - 1024;
  int bx = b & 127, by = b >> 7;  // bx: col tile, by: row tile
  const float* src;
  unsigned short* dst;
  int C;
  if (bx < 96) { src = s1; dst = d1; C = 3072; }
  else         { src = s2; dst = d2; C = 1024; bx -= 96; }
  int xx = tid & 31, yy = tid >> 5;
  int c0 = bx * 32, r0 = by * 32;
  t[yy][xx] = f2b(src[(size_t)(r0 + yy) * C + c0 + xx]);
  __syncthreads();
  dst[(size_t)(c0 + yy) * 1024 + r0 + xx] = t[xx][yy];
}

// ---------- GEMM: C[M,N] = A[M,K] * Bt[N,K]^T (+bias), bf16 MFMA ----------
// R14-exact inner structure. 1D grid with XCD-chunked swizzle: blocks are
// remapped v = (u&7)*CHUNK + (u>>3) so each XCD (round-robin dispatch) owns
// a contiguous run of m-tiles x all n-tiles -> its A-panel slice (~1MB)
// stays resident in the 4MB per-XCD L2 while B streams once. NT = n-tiles.
template <int MODE, int TM, int NT>
__global__ __launch_bounds__(256, 2) void gemm_bf16_kernel(
    const unsigned short* __restrict__ A, const unsigned short* __restrict__ Bt,
    const float* __restrict__ bias, int M, int N, int K,
    unsigned short* __restrict__ q_bf, unsigned short* __restrict__ k_bf,
    unsigned short* __restrict__ vt_bf, float* __restrict__ k_out,
    float* __restrict__ v_out, float* __restrict__ y_out) {
  constexpr int MR = TM / 32;       // A-fragment rows per wave / stage chunks
  __shared__ __align__(16) unsigned short As[TM * 64];
  __shared__ __align__(16) unsigned short Bs[128 * 64];
  const int tid = threadIdx.x;
  const int lane = tid & 63, wid = tid >> 6;
  const int wr = wid >> 1, wc = wid & 1;
  const int l15 = lane & 15, lg = lane >> 4;
  // XCD-chunked swizzle (grid size = 8 * CHUNK, CHUNK = blocks per XCD)
  const int u = (int)blockIdx.x;
  const int v = (u & 7) * ((gridDim.x) >> 3) + (u >> 3);
  const int m0 = (v / NT) * TM, n0 = (v % NT) * 128;

  f32x4 acc[MR][4] = {};

  int rowS[4], colS[4];
#pragma unroll
  for (int j = 0; j < 4; ++j) {
    int L = j * 4096 + tid * 16;  // linear LDS byte
    int row = L >> 7;
    int c = (L & 127) ^ ((row & 7) << 4);
    rowS[j] = row;
    colS[j] = c >> 1;  // bf16 elements
  }

  for (int kt = 0; kt < K; kt += 64) {
    __syncthreads();
#pragma unroll
    for (int j = 0; j < MR; ++j)
      gload16(A + (size_t)(m0 + rowS[j]) * K + kt + colS[j],
              (char*)As + j * 4096 + tid * 16);
#pragma unroll
    for (int j = 0; j < 4; ++j)
      gload16(Bt + (size_t)(n0 + rowS[j]) * K + kt + colS[j],
              (char*)Bs + j * 4096 + tid * 16);
    __syncthreads();

    bf16x8 af[MR][2], bfr[4][2];
#pragma unroll
    for (int i = 0; i < MR; ++i)
#pragma unroll
      for (int kk = 0; kk < 2; ++kk) {
        int ra = wr * (TM / 2) + i * 16 + l15;
        int cb = kk * 64 + lg * 16;
        af[i][kk] = *(const bf16x8*)((const char*)As + ra * 128 + (cb ^ ((ra & 7) << 4)));
      }
#pragma unroll
    for (int i = 0; i < 4; ++i)
#pragma unroll
      for (int kk = 0; kk < 2; ++kk) {
        int rb = wc * 64 + i * 16 + l15;
        int cb = kk * 64 + lg * 16;
        bfr[i][kk] = *(const bf16x8*)((const char*)Bs + rb * 128 + (cb ^ ((rb & 7) << 4)));
      }
#pragma unroll
    for (int mi = 0; mi < MR; ++mi)
#pragma unroll
      for (int ni = 0; ni < 4; ++ni)
#pragma unroll
        for (int kk = 0; kk < 2; ++kk)
          acc[mi][ni] = MFMA16(af[mi][kk], bfr[ni][kk], acc[mi][ni]);
  }

#pragma unroll
  for (int ni = 0; ni < 4; ++ni) {
    int gn = n0 + wc * 64 + ni * 16 + l15;
    float bv = bias[gn];
    if (MODE == 0) {
      int which = gn >> 10, rem = gn & 1023;
      int h = rem >> 6, dh = rem & 63;
#pragma unroll
      for (int mi = 0; mi < MR; ++mi) {
        int gmb = m0 + wr * (TM / 2) + mi * 16 + lg * 4;
#pragma unroll
        for (int r = 0; r < 4; ++r) {
          int gm = gmb + r;
          int b = gm >> 11, t = gm & 2047;
          float val = acc[mi][ni][r] + bv;
          size_t idx = ((size_t)((b * 16 + h) * 2048 + t)) * 64 + dh;
          if (which == 0) {
            q_bf[idx] = f2b(val * 0.18033688f);  // pre-scale by 1/sqrt(64)*log2(e)
          } else if (which == 1) {
            k_out[idx] = val;
            k_bf[idx] = f2b(val);
          } else {
            v_out[idx] = val;
            vt_bf[((size_t)(b * 16 + h) * 64 + dh) * 2048 + t] = f2b(val);
          }
        }
      }
    } else {
#pragma unroll
      for (int mi = 0; mi < MR; ++mi) {
        int gmb = m0 + wr * (TM / 2) + mi * 16 + lg * 4;
#pragma unroll
        for (int r = 0; r < 4; ++r)
          y_out[(size_t)(gmb + r) * N + gn] = acc[mi][ni][r] + bv;
      }
    }
  }
}

// ---------- causal flash attention: split-K, balanced rounds, dbuf ----------
// (unchanged from the passing R19 kernel)
__global__ __launch_bounds__(256, 3) void attn_kernel(
    const unsigned short* __restrict__ qbuf, const unsigned short* __restrict__ kb,
    const unsigned short* __restrict__ vtb, unsigned short* __restrict__ y_att,
    unsigned short* __restrict__ part_o, float2* __restrict__ part_ml) {
  __shared__ __align__(16) char lds_k[2][8192];
  __shared__ __align__(16) char lds_v[2][8192];
  const int tid = threadIdx.x, lane = tid & 63, w = tid >> 6;
  const int u = (int)blockIdx.x;  // 0..767
  int bh, qb, t0, t1, half, isplit;
  if (u < 256) {                  // round 0: first halves (16 tiles)
    isplit = 1; half = 0;
    qb = 8 + (u >> 5); bh = u & 31;
    t0 = 0; t1 = 16;
  } else if (u < 512) {           // round 1: second halves, qb ascending
    int v = u - 256;
    isplit = 1; half = 1;
    qb = 8 + (v >> 5); bh = v & 31;
    t0 = 16; t1 = 2 * qb + 2;
  } else {                        // round 2: whole blocks, qb descending
    int s = u - 512;
    isplit = 0; half = 0;
    qb = 7 - (s >> 5); bh = s & 31;
    t0 = 0; t1 = 2 * qb + 2;
  }
  const int l31 = lane & 31, h = lane >> 5;
  const int qw0 = qb * 128 + w * 32;              // this wave's first q row
  const int qidx = qw0 + l31;
  const size_t base_off = (size_t)bh * (2048 * 64);
  const unsigned short* Q = qbuf + base_off;
  const char* Kb = (const char*)(kb + base_off);   // [2048][128B]
  const char* Vb = (const char*)(vtb + base_off);  // [64][4096B]
  const int my_last = (qw0 + 31) >> 6;  // last tile this wave computes

  int rowS[2], gcS[2];
#pragma unroll
  for (int j = 0; j < 2; ++j) {
    int L = tid * 16 + j * 4096;
    int row = L >> 7;
    rowS[j] = row;
    gcS[j] = (L & 127) ^ ((row & 7) << 4);
  }

#define STAGE(T)                                                                \
  if ((T) < t1) {                                                               \
    const int kv0_ = (T) * 64;                                                  \
    const int buf_ = (T) & 1;                                                   \
    _Pragma("unroll") for (int j = 0; j < 2; ++j) {                             \
      gload16(Kb + (size_t)(kv0_ + rowS[j]) * 128 + gcS[j],                     \
              &lds_k[buf_][j * 4096 + tid * 16]);                               \
      gload16(Vb + (size_t)rowS[j] * 4096 + kv0_ * 2 + gcS[j],                  \
              &lds_v[buf_][j * 4096 + tid * 16]);                               \
    }                                                                           \
  }

  bf16x8 qB[4];
#pragma unroll
  for (int c = 0; c < 4; ++c)
    qB[c] = *(const bf16x8*)(Q + (size_t)(qw0 + l31) * 64 + c * 16 + h * 8);

  f32x16 yacc0 = {}, yacc1 = {};
  float m_run = -1e30f, l_run = 0.f;  // l_run is PER-LANE (half-row partial)
  const int swz = (l31 & 7) << 4;

  STAGE(t0);

  for (int t = t0; t < t1; ++t) {
    __syncthreads();  // drains stage(t) (issued a full iteration ago)
    STAGE(t + 1);

    if (t <= my_last) {
      const char* Kl = lds_k[t & 1];
      const char* Vl = lds_v[t & 1];
      __builtin_amdgcn_s_setprio(1);
      f32x16 st0 = {}, st1 = {};
#pragma unroll
      for (int c = 0; c < 4; ++c) {
        bf16x8 k0 = *(const bf16x8*)(Kl + (size_t)l31 * 128 + ((c * 32 + h * 16) ^ swz));
        st0 = MFMA32(k0, qB[c], st0);
      }
#pragma unroll
      for (int c = 0; c < 4; ++c) {
        bf16x8 k1 = *(const bf16x8*)(Kl + (size_t)(32 + l31) * 128 + ((c * 32 + h * 16) ^ swz));
        st1 = MFMA32(k1, qB[c], st1);
      }
      __builtin_amdgcn_s_setprio(0);

      if (t == my_last) {  // diagonal tile: causal mask, in place
#pragma unroll
        for (int r = 0; r < 16; ++r) {
          int key0 = t * 64 + (r & 3) + 8 * ((r >> 2) & 3) + 4 * h;
          st0[r] = (key0 > qidx) ? -1e30f : st0[r];
          st1[r] = (key0 + 32 > qidx) ? -1e30f : st1[r];
        }
      }
      float mx;
      {
        float v[8];
#pragma unroll
        for (int r = 0; r < 8; ++r)
          v[r] = fmaxf(fmaxf(st0[r], st0[r + 8]), fmaxf(st1[r], st1[r + 8]));
        float a = fmaxf(fmaxf(v[0], v[1]), v[2]);
        float b = fmaxf(fmaxf(v[3], v[4]), v[5]);
        float c = fmaxf(v[6], v[7]);
        mx = fmaxf(fmaxf(a, b), c);
      }
      mx = fmaxf(mx, __shfl_xor(mx, 32));  // cross-half row max
      if (__any(mx > m_run + 8.f)) {  // defer-max
        float mnew = fmaxf(m_run, mx);
        float alpha = exp2f(m_run - mnew);
#pragma unroll
        for (int r = 0; r < 16; ++r) { yacc0[r] *= alpha; yacc1[r] *= alpha; }
        l_run *= alpha;
        m_run = mnew;
      }
      float ls = 0.f;
#pragma unroll
      for (int r = 0; r < 16; ++r) {
        st0[r] = exp2f(st0[r] - m_run);
        ls += st0[r];
      }
#pragma unroll
      for (int r = 0; r < 16; ++r) {
        st1[r] = exp2f(st1[r] - m_run);
        ls += st1[r];
      }
      l_run += ls;  // per-lane; merged across halves after the loop

      U8 pf[4];
      {
        unsigned pk0 = cvtpk(st0[0], st0[1]), pk1 = cvtpk(st0[2], st0[3]);
        unsigned pk2 = cvtpk(st0[4], st0[5]), pk3 = cvtpk(st0[6], st0[7]);
        unsigned pk4 = cvtpk(st0[8], st0[9]), pk5 = cvtpk(st0[10], st0[11]);
        unsigned pk6 = cvtpk(st0[12], st0[13]), pk7 = cvtpk(st0[14], st0[15]);
        swap32(pk0, pk2); swap32(pk1, pk3); swap32(pk4, pk6); swap32(pk5, pk7);
        pf[0].u[0] = pk0; pf[0].u[1] = pk1; pf[0].u[2] = pk2; pf[0].u[3] = pk3;
        pf[1].u[0] = pk4; pf[1].u[1] = pk5; pf[1].u[2] = pk6; pf[1].u[3] = pk7;
        unsigned qk0 = cvtpk(st1[0], st1[1]), qk1 = cvtpk(st1[2], st1[3]);
        unsigned qk2 = cvtpk(st1[4], st1[5]), qk3 = cvtpk(st1[6], st1[7]);
        unsigned qk4 = cvtpk(st1[8], st1[9]), qk5 = cvtpk(st1[10], st1[11]);
        unsigned qk6 = cvtpk(st1[12], st1[13]), qk7 = cvtpk(st1[14], st1[15]);
        swap32(qk0, qk2); swap32(qk1, qk3); swap32(qk4, qk6); swap32(qk5, qk7);
        pf[2].u[0] = qk0; pf[2].u[1] = qk1; pf[2].u[2] = qk2; pf[2].u[3] = qk3;
        pf[3].u[0] = qk4; pf[3].u[1] = qk5; pf[3].u[2] = qk6; pf[3].u[3] = qk7;
      }

      __builtin_amdgcn_s_setprio(1);
#pragma unroll
      for (int c = 0; c < 4; ++c) {
        bf16x8 v0 = *(const bf16x8*)(Vl + (size_t)l31 * 128 + ((c * 32 + h * 16) ^ swz));
        yacc0 = MFMA32(v0, pf[c].v, yacc0);
      }
#pragma unroll
      for (int c = 0; c < 4; ++c) {
        bf16x8 v1 = *(const bf16x8*)(Vl + (size_t)(32 + l31) * 128 + ((c * 32 + h * 16) ^ swz));
        yacc1 = MFMA32(v1, pf[c].v, yacc1);
      }
      __builtin_amdgcn_s_setprio(0);
    }
  }
#undef STAGE

  float l_tot = l_run + __shfl_xor(l_run, 32);
  float inv = 1.f / l_tot;
  if (!isplit) {
    const int b = bh >> 4, head = bh & 15;
    size_t rowb = ((size_t)(b * 2048 + qw0 + l31) * 16 + head) * 64;
#pragma unroll
    for (int rg = 0; rg < 4; ++rg) {
      int d0 = 8 * rg + 4 * h;
      ushort4 o0, o1;
      o0.x = f2b(yacc0[4 * rg + 0] * inv);
      o0.y = f2b(yacc0[4 * rg + 1] * inv);
      o0.z = f2b(yacc0[4 * rg + 2] * inv);
      o0.w = f2b(yacc0[4 * rg + 3] * inv);
      *(ushort4*)(y_att + rowb + d0) = o0;
      o1.x = f2b(yacc1[4 * rg + 0] * inv);
      o1.y = f2b(yacc1[4 * rg + 1] * inv);
      o1.z = f2b(yacc1[4 * rg + 2] * inv);
      o1.w = f2b(yacc1[4 * rg + 3] * inv);
      *(ushort4*)(y_att + rowb + 32 + d0) = o1;
    }
  } else {
    const int p = ((15 - qb) << 5) | bh;  // 0..255
    unsigned short* po = part_o + (size_t)(p * 2 + half) * 8192;
    const int lrow = w * 32 + l31;
    size_t rowb = (size_t)lrow * 64;
#pragma unroll
    for (int rg = 0; rg < 4; ++rg) {
      int d0 = 8 * rg + 4 * h;
      ushort4 o0, o1;
      o0.x = f2b(yacc0[4 * rg + 0] * inv);
      o0.y = f2b(yacc0[4 * rg + 1] * inv);
      o0.z = f2b(yacc0[4 * rg + 2] * inv);
      o0.w = f2b(yacc0[4 * rg + 3] * inv);
      *(ushort4*)(po + rowb + d0) = o0;
      o1.x = f2b(yacc1[4 * rg + 0] * inv);
      o1.y = f2b(yacc1[4 * rg + 1] * inv);
      o1.z = f2b(yacc1[4 * rg + 2] * inv);
      o1.w = f2b(yacc1[4 * rg + 3] * inv);
      *(ushort4*)(po + rowb + 32 + d0) = o1;
    }
    if (h == 0) part_ml[(p * 2 + half) * 128 + lrow] = make_float2(m_run, l_tot);
  }
}

// ---------- merge the two KV-halves of each split output block ----------
__global__ __launch_bounds__(256) void attn_merge_kernel(
    const unsigned short* __restrict__ part_o, const float2* __restrict__ part_ml,
    unsigned short* __restrict__ y_att) {
  const int p = (int)blockIdx.x;  // 0..255
  const int qb = 15 - (p >> 5);
  const int bh = p & 31;
  const int tid = threadIdx.x;
  const int r = tid >> 1;           // 0..127
  const int c0 = (tid & 1) << 5;    // 0 or 32
  const unsigned short* o0 = part_o + (size_t)(p * 2 + 0) * 8192 + r * 64 + c0;
  const unsigned short* o1 = part_o + (size_t)(p * 2 + 1) * 8192 + r * 64 + c0;
  float2 ml0 = part_ml[(p * 2 + 0) * 128 + r];
  float2 ml1 = part_ml[(p * 2 + 1) * 128 + r];
  float mn = fmaxf(ml0.x, ml1.x);
  float w0 = ml0.y * exp2f(ml0.x - mn);
  float w1 = ml1.y * exp2f(ml1.x - mn);
  float inv = 1.f / (w0 + w1);
  w0 *= inv;
  w1 *= inv;
  const int b = bh >> 4, head = bh & 15;
  unsigned short* dst =
      y_att + ((size_t)(b * 2048 + qb * 128 + r) * 16 + head) * 64 + c0;
#pragma unroll
  for (int c = 0; c < 32; c += 4) {
    ushort4 a = *(const ushort4*)(o0 + c);
    ushort4 bb = *(const ushort4*)(o1 + c);
    ushort4 o;
    o.x = f2b(w0 * b2f(a.x) + w1 * b2f(bb.x));
    o.y = f2b(w0 * b2f(a.y) + w1 * b2f(bb.y));
    o.z = f2b(w0 * b2f(a.z) + w1 * b2f(bb.z));
    o.w = f2b(w0 * b2f(a.w) + w1 * b2f(bb.w));
    *(ushort4*)(dst + c) = o;
  }
}

// ---------- launcher ----------
extern "C" void kernel_launch(void* const* d_in, const int* in_sizes, int n_in,
                              void* d_out, int out_size, void* d_ws, size_t ws_size,
                              hipStream_t stream) {
  const float* x = (const float*)d_in[0];
  const float* W_qkv = (const float*)d_in[1];
  const float* b_qkv = (const float*)d_in[2];
  const float* W_out = (const float*)d_in[3];
  const float* b_out = (const float*)d_in[4];

  float* y_out = (float*)d_out;                 // [2,2048,1024]
  float* k_out = y_out + 4194304;               // [2,16,2048,64]
  float* v_out = y_out + 8388608;               // [2,16,2048,64]

  unsigned short* x_bf = (unsigned short*)d_ws;       // [4096,1024]
  unsigned short* wqkv_t = x_bf + 4194304;            // [3072,1024]
  unsigned short* wout_t = wqkv_t + 3145728;          // [1024,1024]
  unsigned short* q_bf = wout_t + 1048576;            // [B,H,T,Dh] (pre-scaled)
  unsigned short* k_bf = q_bf + 4194304;              // [B,H,T,Dh]
  unsigned short* vt_bf = k_bf + 4194304;             // [B,H,Dh,T]
  unsigned short* y_att = vt_bf + 4194304;            // [B,T,H*Dh]

  // attn partial buffers: reuse regions dead after GEMM0 (x_bf, wqkv_t)
  unsigned short* part_o = x_bf;                 // 512 x 8192 ushort = 8 MB
  float2* part_ml = (float2*)wqkv_t;             // 512 x 128 float2 = 512 KB

  prepass_kernel<<<5120, 1024, 0, stream>>>(x, x_bf, W_qkv, wqkv_t, W_out, wout_t);
  gemm_bf16_kernel<0, 128, 24><<<768, 256, 0, stream>>>(
      x_bf, wqkv_t, b_qkv, 4096, 3072, 1024, q_bf, k_bf, vt_bf, k_out, v_out, nullptr);
  attn_kernel<<<768, 256, 0, stream>>>(q_bf, k_bf, vt_bf, y_att, part_o, part_ml);
  attn_merge_kernel<<<256, 256, 0, stream>>>(part_o, part_ml, y_att);
  gemm_bf16_kernel<1, 64, 8><<<512, 256, 0, stream>>>(
      y_att, wout_t, b_out, 4096, 1024, 1024, nullptr, nullptr, nullptr, nullptr, nullptr, y_out);
}